// Round 12
// baseline (257.138 us; speedup 1.0000x reference)
//
#include <hip/hip_runtime.h>
#include <hip/hip_bf16.h>

#define NB 4
#define CH 256
#define HWT 3600
#define KNN 8
#define MPAD 3712

#define SSEGP 16     // knn segments (225 candidates each)
#define CAND 225
#define RB 8         // row-blocks; each block covers 450 rows (225 threads x 2)

#define GEMM_BLKS 928     // 232 * NB

typedef __attribute__((ext_vector_type(8))) __bf16 bf16x8;
typedef __attribute__((ext_vector_type(4))) float f32x4;
typedef __attribute__((ext_vector_type(2))) float f32x2;
typedef __attribute__((ext_vector_type(2))) unsigned u32x2;
typedef __attribute__((ext_vector_type(4))) unsigned u32x4;

__device__ inline float med3f(float a, float b, float c) {
    return __builtin_amdgcn_fmed3f(a, b, c);
}

__device__ __forceinline__ void insert8(float* best, float kf) {
    best[7] = med3f(best[6], best[7], kf);
    best[6] = med3f(best[5], best[6], kf);
    best[5] = med3f(best[4], best[5], kf);
    best[4] = med3f(best[3], best[4], kf);
    best[3] = med3f(best[2], best[3], kf);
    best[2] = med3f(best[1], best[2], kf);
    best[1] = med3f(best[0], best[1], kf);
    best[0] = fminf(best[0], kf);
}

// ================= gemm body =================

__device__ __forceinline__ void gemm_body(int lid, int n,
                                          const __hip_bfloat16* __restrict__ Abf,
                                          const __hip_bfloat16* __restrict__ Wbf,
                                          __hip_bfloat16* __restrict__ Yall,
                                          char* smem) {
    char* sA = smem;
    char* sB = smem + 16384;
    int w = (lid & 7) * 29 + (lid >> 3);
    int m0 = (w >> 3) * 128;
    int o0 = (w & 7) * 128;
    int t = threadIdx.x;
    int lane = t & 63, wid = t >> 6;
    int wm = wid >> 1, wo = wid & 1;

    const __hip_bfloat16* Ab = Abf + (size_t)n * MPAD * CH;
    const __hip_bfloat16* Wb = Wbf + (size_t)n * 1024 * CH;

    f32x4 acc[4][4] = {};

    int srow = t >> 3;
    int sslot = t & 7;
    int swz = (sslot ^ (srow & 7)) << 4;
    int fr = lane & 15;
    int kg = lane >> 4;
    int p = lane & 7;

    uint4 av[4], bv[4];
    auto load_tile = [&](int ks) {
#pragma unroll
        for (int r = 0; r < 4; ++r) {
            int row = srow + 32 * r;
            av[r] = *(const uint4*)(Ab + ((size_t)(m0 + row)) * CH + ks * 64 + sslot * 8);
            bv[r] = *(const uint4*)(Wb + ((size_t)(o0 + row)) * CH + ks * 64 + sslot * 8);
        }
    };
    load_tile(0);

    for (int ks = 0; ks < 4; ++ks) {
        __syncthreads();
#pragma unroll
        for (int r = 0; r < 4; ++r) {
            int row = srow + 32 * r;
            *(uint4*)(sA + row * 128 + swz) = av[r];
            *(uint4*)(sB + row * 128 + swz) = bv[r];
        }
        __syncthreads();
        if (ks < 3) load_tile(ks + 1);
#pragma unroll
        for (int kk = 0; kk < 2; ++kk) {
            bf16x8 hf[4], wf[4];
            int slot = kk * 4 + kg;
            int inrow = (slot ^ p) << 4;
#pragma unroll
            for (int f = 0; f < 4; ++f) {
                hf[f] = *(const bf16x8*)(sA + (wm * 64 + f * 16 + fr) * 128 + inrow);
                wf[f] = *(const bf16x8*)(sB + (wo * 64 + f * 16 + fr) * 128 + inrow);
            }
#pragma unroll
            for (int fa = 0; fa < 4; ++fa)
#pragma unroll
                for (int fb = 0; fb < 4; ++fb)
                    acc[fa][fb] = __builtin_amdgcn_mfma_f32_16x16x32_bf16(
                        wf[fa], hf[fb], acc[fa][fb], 0, 0, 0);
        }
    }

    __syncthreads();
#pragma unroll
    for (int fa = 0; fa < 4; ++fa)
#pragma unroll
        for (int fb = 0; fb < 4; ++fb) {
            int ml = wm * 64 + fb * 16 + fr;
            int ob = (wo * 64 + fa * 16 + kg * 4) * 2;
            f32x4 v = acc[fa][fb];
            union { ushort4 u; __hip_bfloat16 h[4]; } pk;
            pk.h[0] = __float2bfloat16(v.x);
            pk.h[1] = __float2bfloat16(v.y);
            pk.h[2] = __float2bfloat16(v.z);
            pk.h[3] = __float2bfloat16(v.w);
            int swzb = (ob & ~15) ^ ((ml & 15) << 4);
            *(ushort4*)(smem + ml * 256 + swzb + (ob & 15)) = pk.u;
        }
    __syncthreads();
    __hip_bfloat16* Y = Yall + (size_t)n * HWT * 1024;
    int colb = (t & 15) * 16;
#pragma unroll
    for (int i = 0; i < 8; ++i) {
        int row = i * 16 + (t >> 4);
        int grow = m0 + row;
        if (grow < HWT) {
            u32x4 v = *(const u32x4*)(smem + row * 256 + (colb ^ ((row & 15) << 4)));
            __builtin_nontemporal_store(v, (u32x4*)((char*)Y + (size_t)grow * 2048 + o0 * 2 + colb));
        }
    }
}

__global__ __launch_bounds__(256) void gemm_k(const __hip_bfloat16* __restrict__ Abf,
                                              const __hip_bfloat16* __restrict__ Wbf,
                                              __hip_bfloat16* __restrict__ Yall) {
    __shared__ char smem[32768];
    int gid = blockIdx.x;
    gemm_body(gid % 232, gid / 232, Abf, Wbf, Yall, smem);
}

// ================= kNN main v5: row-packed f32x2 (v_pk_fma) + v4 grid =================
// grid (16, 8, 2*NB) = 1024 blocks; block: 225 active threads x 2 rows x 225 cand
__global__ __launch_bounds__(256) void knn_main(const float* __restrict__ xpack,
                                                unsigned* __restrict__ partial) {
    int seg = blockIdx.x, rb = blockIdx.y, nm = blockIdx.z;
    int t = threadIdx.x;
    const float* xp = xpack + (size_t)nm * HWT * 8;
    __shared__ float4 xs4[CAND];
    __shared__ float2 xs2[CAND];
    int j0 = seg * CAND;
    if (t < CAND) {
        float4 a = ((const float4*)xp)[(size_t)(j0 + t) * 2];
        float4 b = ((const float4*)xp)[(size_t)(j0 + t) * 2 + 1];
        xs4[t] = a;
        xs2[t] = float2{b.x, b.y + 1.0f};   // {x4_j, q_j + 1}
    }
    __syncthreads();

    bool active = (t < CAND);
    int r0 = rb * 450 + t;                  // rows r0 and r0+225
    int rr0 = active ? r0 : 0;
    int rr1 = active ? (r0 + CAND) : 0;
    float4 a0 = ((const float4*)xp)[(size_t)rr0 * 2];
    float4 b0 = ((const float4*)xp)[(size_t)rr0 * 2 + 1];
    float4 a1 = ((const float4*)xp)[(size_t)rr1 * 2];
    float4 b1 = ((const float4*)xp)[(size_t)rr1 * 2 + 1];
    f32x2 rx = {a0.x, a1.x};
    f32x2 ry = {a0.y, a1.y};
    f32x2 rz = {a0.z, a1.z};
    f32x2 rw = {a0.w, a1.w};
    f32x2 rv = {b0.x, b1.x};
    f32x2 rq = {b0.y, b1.y};               // q_i per row

    const float BIG = __uint_as_float(0x7F000000u);
    float bst0[8], bst1[8];
#pragma unroll
    for (int i = 0; i < 8; ++i) { bst0[i] = BIG; bst1[i] = BIG; }

    unsigned jg0 = (unsigned)j0;
#pragma unroll 5
    for (int jj = 0; jj < CAND; ++jj) {
        float4 a = xs4[jj];
        float2 b = xs2[jj];                 // {x4_j, q_j+1}
        unsigned jg = jg0 + jj;
        f32x2 d = rx * a.x;                 // v_pk_mul/fma with scalar splat
        d += ry * a.y;
        d += rz * a.z;
        d += rw * a.w;
        d += rv * b.x;
        f32x2 e = (rq + b.y) - 2.0f * d;    // d^2 + 1 >= ~1, both rows
        u32x2 u;
        __builtin_memcpy(&u, &e, 8);
        float k0 = __uint_as_float((u.x & 0xFFFFF000u) | jg);
        float k1 = __uint_as_float((u.y & 0xFFFFF000u) | jg);
        insert8(bst0, k0);
        insert8(bst1, k1);
    }
    if (active) {
        unsigned* o = partial + (((size_t)(nm * SSEGP + seg)) * HWT + r0) * 8;
        ((uint4*)o)[0] = uint4{ __float_as_uint(bst0[0]), __float_as_uint(bst0[1]),
                                __float_as_uint(bst0[2]), __float_as_uint(bst0[3]) };
        ((uint4*)o)[1] = uint4{ __float_as_uint(bst0[4]), __float_as_uint(bst0[5]),
                                __float_as_uint(bst0[6]), __float_as_uint(bst0[7]) };
        unsigned* o1 = partial + (((size_t)(nm * SSEGP + seg)) * HWT + r0 + CAND) * 8;
        ((uint4*)o1)[0] = uint4{ __float_as_uint(bst1[0]), __float_as_uint(bst1[1]),
                                 __float_as_uint(bst1[2]), __float_as_uint(bst1[3]) };
        ((uint4*)o1)[1] = uint4{ __float_as_uint(bst1[4]), __float_as_uint(bst1[5]),
                                 __float_as_uint(bst1[6]), __float_as_uint(bst1[7]) };
    }
}

// ================= fusedA prolog =================
__global__ __launch_bounds__(256) void fusedA(const float* __restrict__ cnn,
                                              __hip_bfloat16* __restrict__ Abf,
                                              const float* __restrict__ Wg_rgb,
                                              const float* __restrict__ Wg_ir,
                                              float* __restrict__ Wcomb,
                                              float* __restrict__ g,
                                              __hip_bfloat16* __restrict__ Wbf,
                                              const float* __restrict__ rgb,
                                              const float* __restrict__ ir,
                                              float* __restrict__ xpack) {
    int bid = blockIdx.x;
    int t = threadIdx.x;
    if (bid < GEMM_BLKS) {
        __shared__ float st[64][65];
        int n = bid / 232;
        int rem = bid - n * 232;
        int k0 = (rem / 58) * 64;
        int m0 = (rem % 58) * 64;
        const float* src = cnn + (size_t)n * CH * HWT;
#pragma unroll
        for (int r = 0; r < 4; ++r) {
            int kl = r * 16 + (t >> 4);
            int ms = (t & 15) * 4;
            float4 v = {0.f, 0.f, 0.f, 0.f};
            if (m0 + ms < HWT) v = *(const float4*)(src + (size_t)(k0 + kl) * HWT + m0 + ms);
            st[ms + 0][kl] = v.x; st[ms + 1][kl] = v.y;
            st[ms + 2][kl] = v.z; st[ms + 3][kl] = v.w;
        }
        __syncthreads();
        int m = t >> 2, kg = (t & 3) * 16;
        union { uint4 u[2]; __hip_bfloat16 h[16]; } pk;
#pragma unroll
        for (int i = 0; i < 16; ++i) pk.h[i] = __float2bfloat16(st[m][kg + i]);
        __hip_bfloat16* dst = Abf + ((size_t)n * MPAD + m0 + m) * CH + k0 + kg;
        ((uint4*)dst)[0] = pk.u[0];
        ((uint4*)dst)[1] = pk.u[1];
    } else if (bid < GEMM_BLKS + 1024) {
        int e = (bid - GEMM_BLKS) * 256 + t;
        int o = e >> 8, j = e & 255;
        float v;
        if (o < 256)      v = Wg_rgb[o * 512 + j] + Wg_rgb[o * 512 + 256 + j];
        else if (o < 512) v = Wg_rgb[(o - 256) * 512 + 256 + j];
        else if (o < 768) v = Wg_ir[(o - 512) * 512 + j] + Wg_ir[(o - 512) * 512 + 256 + j];
        else              v = Wg_ir[(o - 768) * 512 + 256 + j];
        Wcomb[e] = v;
        __hip_bfloat16 h = __float2bfloat16(v);   // iter0: g == 1
#pragma unroll
        for (int n = 0; n < NB; ++n) Wbf[(size_t)n * 262144 + e] = h;
        if (e < NB * CH) g[e] = 1.0f;
    } else {
        int e = (bid - GEMM_BLKS - 1024) * 256 + t;
        if (e < 2 * NB * HWT) {
            int nm = e / HWT, j = e - nm * HWT;
            int mod = nm / NB, n = nm - mod * NB;
            const float* x = (mod == 0 ? rgb : ir) + (size_t)n * 5 * HWT;
            float v[5], q = 0.f;
#pragma unroll
            for (int d = 0; d < 5; ++d) { v[d] = x[d * HWT + j]; q = fmaf(v[d], v[d], q); }
            float* o = xpack + (size_t)e * 8;
#pragma unroll
            for (int d = 0; d < 5; ++d) o[d] = v[d];
            o[5] = q; o[6] = 0.f; o[7] = 0.f;
        }
    }
}

// ================= merge + zero =================
__global__ __launch_bounds__(256) void knn_merge_zero(const unsigned* __restrict__ partial,
                                                      int* __restrict__ knn_rgb,
                                                      int* __restrict__ knn_ir,
                                                      float* __restrict__ ccsum) {
    int bid = blockIdx.x;
    if (bid >= 450) {
        int e = (bid - 450) * 256 + threadIdx.x;
        if (e < NB * 512) ccsum[e] = 0.f;
        return;
    }
    int tid = bid * 256 + threadIdx.x;
    int rid = tid >> 1, sub = tid & 1;
    int nm = rid / HWT, row = rid - nm * HWT;
    const float BIG = __uint_as_float(0x7F000000u);
    float best[8];
#pragma unroll
    for (int i = 0; i < 8; ++i) best[i] = BIG;
    for (int s = sub; s < SSEGP; s += 2) {
        const unsigned* p = partial + (((size_t)(nm * SSEGP + s)) * HWT + row) * 8;
#pragma unroll
        for (int w = 0; w < 2; ++w) {
            uint4 v = ((const uint4*)p)[w];
            unsigned vv[4] = { v.x, v.y, v.z, v.w };
#pragma unroll
            for (int e = 0; e < 4; ++e) insert8(best, __uint_as_float(vv[e]));
        }
    }
    float other[8];
#pragma unroll
    for (int i = 0; i < 8; ++i) other[i] = __shfl_xor(best[i], 1);
#pragma unroll
    for (int i = 0; i < 8; ++i) insert8(best, other[i]);
    if (sub == 0) {
        int mod = nm / NB, n = nm - mod * NB;
        int* o = (mod == 0 ? knn_rgb : knn_ir) + ((size_t)n * HWT + row) * KNN;
#pragma unroll
        for (int i = 0; i < 8; ++i) o[i] = (int)(__float_as_uint(best[i]) & 0xFFFu);
    }
}

// ================= scale_w + zero =================
__global__ __launch_bounds__(256) void scale_w_zero(const float* __restrict__ Wcomb,
                                                    const float* __restrict__ g,
                                                    __hip_bfloat16* __restrict__ Wbf,
                                                    float* __restrict__ ccsum) {
    int bid = blockIdx.x;
    if (bid >= 512) {
        int e = (bid - 512) * 256 + threadIdx.x;
        if (e < NB * 512) ccsum[e] = 0.f;
        return;
    }
    int n = bid >> 7;
    int gid = (bid & 127) * 256 + threadIdx.x;
    int o = gid >> 5;
    int kb = (gid & 31) * 8;
    const float* w = Wcomb + o * 256 + kb;
    const float* gp = g + n * CH + kb;
    union { uint4 u; __hip_bfloat16 h[8]; } pk;
#pragma unroll
    for (int i = 0; i < 8; ++i) pk.h[i] = __float2bfloat16(w[i] * gp[i]);
    *(uint4*)(Wbf + ((size_t)n * 1024 + o) * CH + kb) = pk.u;
}

// ================= gather: two channel passes (hc), L2-resident window =================
// grid 900/pass; block: 16 pos; threads = modality(2) x psub(2) x chpair(64)
__global__ __launch_bounds__(256) void gather_kernel(const __hip_bfloat16* __restrict__ Yall,
                                                     const int* __restrict__ knn_rgb,
                                                     const int* __restrict__ knn_ir,
                                                     const float* __restrict__ b_rgb,
                                                     const float* __restrict__ b_ir,
                                                     float* __restrict__ ccsum, int hc) {
    int lid = blockIdx.x;                 // 0..899
    int xcd = lid & 7, sub_ = lid >> 3;   // 900 = 8*112 + 4
    int wg = (xcd < 4 ? xcd * 113 : 452 + (xcd - 4) * 112) + sub_;
    int n = wg / 225;
    int hwbase = (wg - n * 225) * 16;
    int t = threadIdx.x;
    int half = t >> 7;                    // modality
    int psub = (t >> 6) & 1;              // position subgroup
    int pr = t & 63;                      // channel-pair index
    int cp = hc * 128 + pr * 2;
    __shared__ int sidx[16][2][KNN];
    __shared__ float red[2][64][2];
    {
        int p = t >> 4, rem = t & 15;
        int hw = hwbase + p;
        int v;
        if (rem < 8) v = knn_rgb[((size_t)n * HWT + hw) * KNN + rem];
        else         v = knn_ir[((size_t)n * HWT + hw) * KNN + (rem - 8)];
        sidx[p][rem >> 3][rem & 7] = v;
    }
    __syncthreads();
    const float* bias = half ? b_ir : b_rgb;
    float bb0 = bias[cp], bb1 = bias[cp + 1];
    float acc0 = 0.f, acc1 = 0.f;
    const __hip_bfloat16* Y = Yall + (size_t)n * HWT * 1024;
    int offA = half * 512 + cp;
    int offB = half * 512 + 256 + cp;
    for (int p = psub * 8; p < psub * 8 + 8; ++p) {
        float m0 = 0.f, m1 = 0.f;
#pragma unroll
        for (int k = 0; k < KNN; ++k) {
            int jA = sidx[p][half][k];
            int jB = sidx[p][half ^ 1][k];
            unsigned u1 = *(const unsigned*)(Y + (size_t)jA * 1024 + offA);
            unsigned u2 = *(const unsigned*)(Y + (size_t)jB * 1024 + offB);
            float a0 = __uint_as_float(u1 << 16);
            float a1 = __uint_as_float(u1 & 0xFFFF0000u);
            float c0 = __uint_as_float(u2 << 16);
            float c1 = __uint_as_float(u2 & 0xFFFF0000u);
            m0 = fmaxf(m0, a0 - c0 + bb0);
            m1 = fmaxf(m1, a1 - c1 + bb1);
        }
        acc0 += m0;
        acc1 += m1;
    }
    if (psub) { red[half][pr][0] = acc0; red[half][pr][1] = acc1; }
    __syncthreads();
    if (!psub) {
        acc0 += red[half][pr][0];
        acc1 += red[half][pr][1];
        atomicAdd(&ccsum[n * 512 + half * 256 + cp], acc0);
        atomicAdd(&ccsum[n * 512 + half * 256 + cp + 1], acc1);
    }
}

__global__ __launch_bounds__(256) void se_kernel(const float* __restrict__ ccsum,
                                                 const float* __restrict__ W1,
                                                 const float* __restrict__ b1,
                                                 const float* __restrict__ W2,
                                                 const float* __restrict__ b2,
                                                 float* __restrict__ g) {
    int n = blockIdx.x;
    int t = threadIdx.x;
    __shared__ float hid[16];
    __shared__ float cc[512];
    cc[t] = ccsum[n * 512 + t] * (1.0f / HWT);
    cc[256 + t] = ccsum[n * 512 + 256 + t] * (1.0f / HWT);
    __syncthreads();
    if (t < 16) {
        float s = b1[t];
        for (int j = 0; j < 512; ++j) s = fmaf(W1[t * 512 + j], cc[j], s);
        hid[t] = fmaxf(s, 0.f);
    }
    __syncthreads();
    float s = b2[t];
#pragma unroll
    for (int q = 0; q < 16; ++q) s = fmaf(W2[t * 16 + q], hid[q], s);
    float se = 1.0f / (1.0f + expf(-s));
    g[n * CH + t] *= se;
}

__global__ void final_kernel(const float* __restrict__ cnn, const float* __restrict__ g,
                             const float* __restrict__ gamma, float* __restrict__ out) {
    int t = blockIdx.x * blockDim.x + threadIdx.x;
    if (t >= NB * CH * HWT / 4) return;
    int nc = (t * 4) / HWT;
    float4 x = ((const float4*)cnn)[t];
    float s = gamma[0] * g[nc] + 1.0f;
    float4 o;
    o.x = fmaxf(s * x.x, 0.f);
    o.y = fmaxf(s * x.y, 0.f);
    o.z = fmaxf(s * x.z, 0.f);
    o.w = fmaxf(s * x.w, 0.f);
    ((float4*)out)[t] = o;
}

extern "C" void kernel_launch(void* const* d_in, const int* in_sizes, int n_in,
                              void* d_out, int out_size, void* d_ws, size_t ws_size,
                              hipStream_t stream) {
    const float* cnn    = (const float*)d_in[0];
    const float* rgb    = (const float*)d_in[1];
    const float* ir     = (const float*)d_in[2];
    const float* Wg_rgb = (const float*)d_in[3];
    const float* bg_rgb = (const float*)d_in[4];
    const float* Wg_ir  = (const float*)d_in[5];
    const float* bg_ir  = (const float*)d_in[6];
    const float* Wse1   = (const float*)d_in[7];
    const float* bse1   = (const float*)d_in[8];
    const float* Wse2   = (const float*)d_in[9];
    const float* bse2   = (const float*)d_in[10];
    const float* gamma  = (const float*)d_in[11];
    float* out = (float*)d_out;

    char* ws = (char*)d_ws;
    size_t off = 0;
    float* xpack = (float*)(ws + off); off += (size_t)2 * NB * HWT * 8 * 4;
    int* knn_rgb = (int*)(ws + off); off += (size_t)NB * HWT * KNN * 4;
    int* knn_ir  = (int*)(ws + off); off += (size_t)NB * HWT * KNN * 4;
    float* Wcomb = (float*)(ws + off); off += (size_t)1024 * 256 * 4;
    __hip_bfloat16* Wbf = (__hip_bfloat16*)(ws + off); off += (size_t)NB * 1024 * CH * 2;
    __hip_bfloat16* Abf = (__hip_bfloat16*)(ws + off); off += (size_t)NB * MPAD * CH * 2;
    __hip_bfloat16* Yall = (__hip_bfloat16*)(ws + off); off += (size_t)NB * HWT * 1024 * 2;
    unsigned* partial = (unsigned*)(ws + off);
    off += (size_t)2 * NB * SSEGP * HWT * 8 * 4;     // 14.7 MB
    float* ccsum = (float*)(ws + off); off += (size_t)NB * 512 * 4;
    float* g     = (float*)(ws + off); off += (size_t)NB * CH * 4;

    // prolog: convert_a + Wcomb/Wbf(it0)/g + knn_prep
    fusedA<<<GEMM_BLKS + 1024 + 113, 256, 0, stream>>>(cnn, Abf, Wg_rgb, Wg_ir, Wcomb, g,
                                                       Wbf, rgb, ir, xpack);
    knn_main<<<dim3(SSEGP, RB, 2 * NB), 256, 0, stream>>>(xpack, partial);
    gemm_k<<<GEMM_BLKS, 256, 0, stream>>>(Abf, Wbf, Yall);
    knn_merge_zero<<<458, 256, 0, stream>>>(partial, knn_rgb, knn_ir, ccsum);
    gather_kernel<<<900, 256, 0, stream>>>(Yall, knn_rgb, knn_ir, bg_rgb, bg_ir, ccsum, 0);
    gather_kernel<<<900, 256, 0, stream>>>(Yall, knn_rgb, knn_ir, bg_rgb, bg_ir, ccsum, 1);
    se_kernel<<<NB, 256, 0, stream>>>(ccsum, Wse1, bse1, Wse2, bse2, g);
    // iter 1
    scale_w_zero<<<520, 256, 0, stream>>>(Wcomb, g, Wbf, ccsum);
    gemm_k<<<GEMM_BLKS, 256, 0, stream>>>(Abf, Wbf, Yall);
    gather_kernel<<<900, 256, 0, stream>>>(Yall, knn_rgb, knn_ir, bg_rgb, bg_ir, ccsum, 0);
    gather_kernel<<<900, 256, 0, stream>>>(Yall, knn_rgb, knn_ir, bg_rgb, bg_ir, ccsum, 1);
    se_kernel<<<NB, 256, 0, stream>>>(ccsum, Wse1, bse1, Wse2, bse2, g);
    final_kernel<<<3600, 256, 0, stream>>>(cnn, g, gamma, out);
}

// Round 13
// 226.483 us; speedup vs baseline: 1.1354x; 1.1354x over previous
//
#include <hip/hip_runtime.h>
#include <hip/hip_bf16.h>

#define NB 4
#define CH 256
#define HWT 3600
#define KNN 8
#define POSB 16
#define MPAD 3712

#define SSEGP 16     // knn segments (225 candidates each)
#define CAND 225
#define RROWS 512    // rows per block: 256 threads x 2

#define GEMM_BLKS 928     // 232 * NB

typedef __attribute__((ext_vector_type(8))) __bf16 bf16x8;
typedef __attribute__((ext_vector_type(4))) float f32x4;
typedef __attribute__((ext_vector_type(4))) unsigned u32x4;

__device__ inline float med3f(float a, float b, float c) {
    return __builtin_amdgcn_fmed3f(a, b, c);
}

__device__ __forceinline__ void insert8(float* best, float kf) {
    best[7] = med3f(best[6], best[7], kf);
    best[6] = med3f(best[5], best[6], kf);
    best[5] = med3f(best[4], best[5], kf);
    best[4] = med3f(best[3], best[4], kf);
    best[3] = med3f(best[2], best[3], kf);
    best[2] = med3f(best[1], best[2], kf);
    best[1] = med3f(best[0], best[1], kf);
    best[0] = fminf(best[0], kf);
}

// ================= gemm body =================

__device__ __forceinline__ void gemm_body(int lid, int n,
                                          const __hip_bfloat16* __restrict__ Abf,
                                          const __hip_bfloat16* __restrict__ Wbf,
                                          __hip_bfloat16* __restrict__ Yall,
                                          char* smem) {
    char* sA = smem;
    char* sB = smem + 16384;
    int w = (lid & 7) * 29 + (lid >> 3);
    int m0 = (w >> 3) * 128;
    int o0 = (w & 7) * 128;
    int t = threadIdx.x;
    int lane = t & 63, wid = t >> 6;
    int wm = wid >> 1, wo = wid & 1;

    const __hip_bfloat16* Ab = Abf + (size_t)n * MPAD * CH;
    const __hip_bfloat16* Wb = Wbf + (size_t)n * 1024 * CH;

    f32x4 acc[4][4] = {};

    int srow = t >> 3;
    int sslot = t & 7;
    int swz = (sslot ^ (srow & 7)) << 4;
    int fr = lane & 15;
    int kg = lane >> 4;
    int p = lane & 7;

    uint4 av[4], bv[4];
    auto load_tile = [&](int ks) {
#pragma unroll
        for (int r = 0; r < 4; ++r) {
            int row = srow + 32 * r;
            av[r] = *(const uint4*)(Ab + ((size_t)(m0 + row)) * CH + ks * 64 + sslot * 8);
            bv[r] = *(const uint4*)(Wb + ((size_t)(o0 + row)) * CH + ks * 64 + sslot * 8);
        }
    };
    load_tile(0);

    for (int ks = 0; ks < 4; ++ks) {
        __syncthreads();
#pragma unroll
        for (int r = 0; r < 4; ++r) {
            int row = srow + 32 * r;
            *(uint4*)(sA + row * 128 + swz) = av[r];
            *(uint4*)(sB + row * 128 + swz) = bv[r];
        }
        __syncthreads();
        if (ks < 3) load_tile(ks + 1);
#pragma unroll
        for (int kk = 0; kk < 2; ++kk) {
            bf16x8 hf[4], wf[4];
            int slot = kk * 4 + kg;
            int inrow = (slot ^ p) << 4;
#pragma unroll
            for (int f = 0; f < 4; ++f) {
                hf[f] = *(const bf16x8*)(sA + (wm * 64 + f * 16 + fr) * 128 + inrow);
                wf[f] = *(const bf16x8*)(sB + (wo * 64 + f * 16 + fr) * 128 + inrow);
            }
#pragma unroll
            for (int fa = 0; fa < 4; ++fa)
#pragma unroll
                for (int fb = 0; fb < 4; ++fb)
                    acc[fa][fb] = __builtin_amdgcn_mfma_f32_16x16x32_bf16(
                        wf[fa], hf[fb], acc[fa][fb], 0, 0, 0);
        }
    }

    __syncthreads();
#pragma unroll
    for (int fa = 0; fa < 4; ++fa)
#pragma unroll
        for (int fb = 0; fb < 4; ++fb) {
            int ml = wm * 64 + fb * 16 + fr;
            int ob = (wo * 64 + fa * 16 + kg * 4) * 2;
            f32x4 v = acc[fa][fb];
            union { ushort4 u; __hip_bfloat16 h[4]; } pk;
            pk.h[0] = __float2bfloat16(v.x);
            pk.h[1] = __float2bfloat16(v.y);
            pk.h[2] = __float2bfloat16(v.z);
            pk.h[3] = __float2bfloat16(v.w);
            int swzb = (ob & ~15) ^ ((ml & 15) << 4);
            *(ushort4*)(smem + ml * 256 + swzb + (ob & 15)) = pk.u;
        }
    __syncthreads();
    __hip_bfloat16* Y = Yall + (size_t)n * HWT * 1024;
    int colb = (t & 15) * 16;
#pragma unroll
    for (int i = 0; i < 8; ++i) {
        int row = i * 16 + (t >> 4);
        int grow = m0 + row;
        if (grow < HWT) {
            u32x4 v = *(const u32x4*)(smem + row * 256 + (colb ^ ((row & 15) << 4)));
            __builtin_nontemporal_store(v, (u32x4*)((char*)Y + (size_t)grow * 2048 + o0 * 2 + colb));
        }
    }
}

__global__ __launch_bounds__(256) void gemm_k(const __hip_bfloat16* __restrict__ Abf,
                                              const __hip_bfloat16* __restrict__ Wbf,
                                              __hip_bfloat16* __restrict__ Yall) {
    __shared__ char smem[32768];
    int gid = blockIdx.x;
    gemm_body(gid % 232, gid / 232, Abf, Wbf, Yall, smem);
}

// ================= kNN main v6: v4 structure, 256 full threads, pre-scaled cands =================
// grid (16, 8, 2*NB) = 1024 blocks; block: 256 threads x 2 rows x 225 cand
__global__ __launch_bounds__(256) void knn_main(const float* __restrict__ xpack,
                                                unsigned* __restrict__ partial) {
    int seg = blockIdx.x, rb = blockIdx.y, nm = blockIdx.z;
    int t = threadIdx.x;
    const float* xp = xpack + (size_t)nm * HWT * 8;
    __shared__ float4 xs4[CAND];     // -2 * x_j (dims 0..3)
    __shared__ float2 xs2[CAND];     // {-2 * x4_j, q_j}
    int j0 = seg * CAND;
    if (t < CAND) {
        float4 a = ((const float4*)xp)[(size_t)(j0 + t) * 2];
        float4 b = ((const float4*)xp)[(size_t)(j0 + t) * 2 + 1];
        xs4[t] = float4{-2.f * a.x, -2.f * a.y, -2.f * a.z, -2.f * a.w};
        xs2[t] = float2{-2.f * b.x, b.y};
    }
    __syncthreads();

    int r0 = rb * RROWS + t;                // rows r0 and r0+256
    int r1 = r0 + 256;
    bool act0 = (r0 < HWT);
    bool act1 = (r1 < HWT);
    int rr0 = act0 ? r0 : 0;
    int rr1 = act1 ? r1 : 0;
    float4 a0 = ((const float4*)xp)[(size_t)rr0 * 2];
    float4 b0 = ((const float4*)xp)[(size_t)rr0 * 2 + 1];
    float4 a1 = ((const float4*)xp)[(size_t)rr1 * 2];
    float4 b1 = ((const float4*)xp)[(size_t)rr1 * 2 + 1];
    float rq0 = b0.y + 1.0f, rq1 = b1.y + 1.0f;   // q_i + 1 per row

    const float BIG = __uint_as_float(0x7F000000u);
    float bst0[8], bst1[8];
#pragma unroll
    for (int i = 0; i < 8; ++i) { bst0[i] = BIG; bst1[i] = BIG; }

    unsigned jg0 = (unsigned)j0;
#pragma unroll 5
    for (int jj = 0; jj < CAND; ++jj) {
        float4 a = xs4[jj];                 // -2x_j
        float2 b = xs2[jj];                 // {-2x4_j, q_j}
        unsigned jg = jg0 + jj;
        // row 0: e = (q_i+1) - 2*dot + q_j
        float d0 = fmaf(a.x, a0.x, rq0);
        d0 = fmaf(a.y, a0.y, d0);
        d0 = fmaf(a.z, a0.z, d0);
        d0 = fmaf(a.w, a0.w, d0);
        d0 = fmaf(b.x, b0.x, d0);
        float e0 = d0 + b.y;
        // row 1
        float d1 = fmaf(a.x, a1.x, rq1);
        d1 = fmaf(a.y, a1.y, d1);
        d1 = fmaf(a.z, a1.z, d1);
        d1 = fmaf(a.w, a1.w, d1);
        d1 = fmaf(b.x, b1.x, d1);
        float e1 = d1 + b.y;
        float k0 = __uint_as_float((__float_as_uint(e0) & 0xFFFFF000u) | jg);
        float k1 = __uint_as_float((__float_as_uint(e1) & 0xFFFFF000u) | jg);
        insert8(bst0, k0);
        insert8(bst1, k1);
    }
    if (act0) {
        unsigned* o = partial + (((size_t)(nm * SSEGP + seg)) * HWT + r0) * 8;
        ((uint4*)o)[0] = uint4{ __float_as_uint(bst0[0]), __float_as_uint(bst0[1]),
                                __float_as_uint(bst0[2]), __float_as_uint(bst0[3]) };
        ((uint4*)o)[1] = uint4{ __float_as_uint(bst0[4]), __float_as_uint(bst0[5]),
                                __float_as_uint(bst0[6]), __float_as_uint(bst0[7]) };
    }
    if (act1) {
        unsigned* o1 = partial + (((size_t)(nm * SSEGP + seg)) * HWT + r1) * 8;
        ((uint4*)o1)[0] = uint4{ __float_as_uint(bst1[0]), __float_as_uint(bst1[1]),
                                 __float_as_uint(bst1[2]), __float_as_uint(bst1[3]) };
        ((uint4*)o1)[1] = uint4{ __float_as_uint(bst1[4]), __float_as_uint(bst1[5]),
                                 __float_as_uint(bst1[6]), __float_as_uint(bst1[7]) };
    }
}

// ================= fusedA prolog =================
__global__ __launch_bounds__(256) void fusedA(const float* __restrict__ cnn,
                                              __hip_bfloat16* __restrict__ Abf,
                                              const float* __restrict__ Wg_rgb,
                                              const float* __restrict__ Wg_ir,
                                              float* __restrict__ Wcomb,
                                              float* __restrict__ g,
                                              __hip_bfloat16* __restrict__ Wbf,
                                              const float* __restrict__ rgb,
                                              const float* __restrict__ ir,
                                              float* __restrict__ xpack) {
    int bid = blockIdx.x;
    int t = threadIdx.x;
    if (bid < GEMM_BLKS) {
        __shared__ float st[64][65];
        int n = bid / 232;
        int rem = bid - n * 232;
        int k0 = (rem / 58) * 64;
        int m0 = (rem % 58) * 64;
        const float* src = cnn + (size_t)n * CH * HWT;
#pragma unroll
        for (int r = 0; r < 4; ++r) {
            int kl = r * 16 + (t >> 4);
            int ms = (t & 15) * 4;
            float4 v = {0.f, 0.f, 0.f, 0.f};
            if (m0 + ms < HWT) v = *(const float4*)(src + (size_t)(k0 + kl) * HWT + m0 + ms);
            st[ms + 0][kl] = v.x; st[ms + 1][kl] = v.y;
            st[ms + 2][kl] = v.z; st[ms + 3][kl] = v.w;
        }
        __syncthreads();
        int m = t >> 2, kg = (t & 3) * 16;
        union { uint4 u[2]; __hip_bfloat16 h[16]; } pk;
#pragma unroll
        for (int i = 0; i < 16; ++i) pk.h[i] = __float2bfloat16(st[m][kg + i]);
        __hip_bfloat16* dst = Abf + ((size_t)n * MPAD + m0 + m) * CH + k0 + kg;
        ((uint4*)dst)[0] = pk.u[0];
        ((uint4*)dst)[1] = pk.u[1];
    } else if (bid < GEMM_BLKS + 1024) {
        int e = (bid - GEMM_BLKS) * 256 + t;
        int o = e >> 8, j = e & 255;
        float v;
        if (o < 256)      v = Wg_rgb[o * 512 + j] + Wg_rgb[o * 512 + 256 + j];
        else if (o < 512) v = Wg_rgb[(o - 256) * 512 + 256 + j];
        else if (o < 768) v = Wg_ir[(o - 512) * 512 + j] + Wg_ir[(o - 512) * 512 + 256 + j];
        else              v = Wg_ir[(o - 768) * 512 + 256 + j];
        Wcomb[e] = v;
        __hip_bfloat16 h = __float2bfloat16(v);   // iter0: g == 1
#pragma unroll
        for (int n = 0; n < NB; ++n) Wbf[(size_t)n * 262144 + e] = h;
        if (e < NB * CH) g[e] = 1.0f;
    } else {
        int e = (bid - GEMM_BLKS - 1024) * 256 + t;
        if (e < 2 * NB * HWT) {
            int nm = e / HWT, j = e - nm * HWT;
            int mod = nm / NB, n = nm - mod * NB;
            const float* x = (mod == 0 ? rgb : ir) + (size_t)n * 5 * HWT;
            float v[5], q = 0.f;
#pragma unroll
            for (int d = 0; d < 5; ++d) { v[d] = x[d * HWT + j]; q = fmaf(v[d], v[d], q); }
            float* o = xpack + (size_t)e * 8;
#pragma unroll
            for (int d = 0; d < 5; ++d) o[d] = v[d];
            o[5] = q; o[6] = 0.f; o[7] = 0.f;
        }
    }
}

// ================= merge + zero =================
__global__ __launch_bounds__(256) void knn_merge_zero(const unsigned* __restrict__ partial,
                                                      int* __restrict__ knn_rgb,
                                                      int* __restrict__ knn_ir,
                                                      float* __restrict__ ccsum) {
    int bid = blockIdx.x;
    if (bid >= 450) {
        int e = (bid - 450) * 256 + threadIdx.x;
        if (e < NB * 512) ccsum[e] = 0.f;
        return;
    }
    int tid = bid * 256 + threadIdx.x;
    int rid = tid >> 1, sub = tid & 1;
    int nm = rid / HWT, row = rid - nm * HWT;
    const float BIG = __uint_as_float(0x7F000000u);
    float best[8];
#pragma unroll
    for (int i = 0; i < 8; ++i) best[i] = BIG;
    for (int s = sub; s < SSEGP; s += 2) {
        const unsigned* p = partial + (((size_t)(nm * SSEGP + s)) * HWT + row) * 8;
#pragma unroll
        for (int w = 0; w < 2; ++w) {
            uint4 v = ((const uint4*)p)[w];
            unsigned vv[4] = { v.x, v.y, v.z, v.w };
#pragma unroll
            for (int e = 0; e < 4; ++e) insert8(best, __uint_as_float(vv[e]));
        }
    }
    float other[8];
#pragma unroll
    for (int i = 0; i < 8; ++i) other[i] = __shfl_xor(best[i], 1);
#pragma unroll
    for (int i = 0; i < 8; ++i) insert8(best, other[i]);
    if (sub == 0) {
        int mod = nm / NB, n = nm - mod * NB;
        int* o = (mod == 0 ? knn_rgb : knn_ir) + ((size_t)n * HWT + row) * KNN;
#pragma unroll
        for (int i = 0; i < 8; ++i) o[i] = (int)(__float_as_uint(best[i]) & 0xFFFu);
    }
}

// ================= scale_w + zero =================
__global__ __launch_bounds__(256) void scale_w_zero(const float* __restrict__ Wcomb,
                                                    const float* __restrict__ g,
                                                    __hip_bfloat16* __restrict__ Wbf,
                                                    float* __restrict__ ccsum) {
    int bid = blockIdx.x;
    if (bid >= 512) {
        int e = (bid - 512) * 256 + threadIdx.x;
        if (e < NB * 512) ccsum[e] = 0.f;
        return;
    }
    int n = bid >> 7;
    int gid = (bid & 127) * 256 + threadIdx.x;
    int o = gid >> 5;
    int kb = (gid & 31) * 8;
    const float* w = Wcomb + o * 256 + kb;
    const float* gp = g + n * CH + kb;
    union { uint4 u; __hip_bfloat16 h[8]; } pk;
#pragma unroll
    for (int i = 0; i < 8; ++i) pk.h[i] = __float2bfloat16(w[i] * gp[i]);
    *(uint4*)(Wbf + ((size_t)n * 1024 + o) * CH + kb) = pk.u;
}

// ================= gather / SE / final (round-11 single-pass form) =================
__global__ __launch_bounds__(256) void gather_kernel(const __hip_bfloat16* __restrict__ Yall,
                                                     const int* __restrict__ knn_rgb,
                                                     const int* __restrict__ knn_ir,
                                                     const float* __restrict__ b_rgb,
                                                     const float* __restrict__ b_ir,
                                                     float* __restrict__ ccsum) {
    int lid = blockIdx.x;                 // 0..899
    int xcd = lid & 7, sub = lid >> 3;    // 900 = 8*112 + 4
    int wg = (xcd < 4 ? xcd * 113 : 4 * 113 + (xcd - 4) * 112) + sub;
    int n = wg / 225;
    int hwbase = (wg - n * 225) * POSB;
    int t = threadIdx.x;
    int half = t >> 7;
    int cp = (t & 127) << 1;
    __shared__ int sidx[POSB][2][KNN];
    {
        int p = t >> 4, rem = t & 15;
        int hw = hwbase + p;
        int v;
        if (rem < 8) v = knn_rgb[((size_t)n * HWT + hw) * KNN + rem];
        else         v = knn_ir[((size_t)n * HWT + hw) * KNN + (rem - 8)];
        sidx[p][rem >> 3][rem & 7] = v;
    }
    __syncthreads();
    const float* bias = half ? b_ir : b_rgb;
    float b0 = bias[cp], b1 = bias[cp + 1];
    float acc0 = 0.f, acc1 = 0.f;
    const __hip_bfloat16* Y = Yall + (size_t)n * HWT * 1024;
    int offA = half * 512 + cp;
    int offB = half * 512 + 256 + cp;
    for (int p = 0; p < POSB; ++p) {
        float m0 = 0.f, m1 = 0.f;
#pragma unroll
        for (int k = 0; k < KNN; ++k) {
            int jA = sidx[p][half][k];
            int jB = sidx[p][half ^ 1][k];
            unsigned u1 = *(const unsigned*)(Y + (size_t)jA * 1024 + offA);
            unsigned u2 = *(const unsigned*)(Y + (size_t)jB * 1024 + offB);
            float a0 = __uint_as_float(u1 << 16);
            float a1 = __uint_as_float(u1 & 0xFFFF0000u);
            float c0 = __uint_as_float(u2 << 16);
            float c1 = __uint_as_float(u2 & 0xFFFF0000u);
            m0 = fmaxf(m0, a0 - c0 + b0);
            m1 = fmaxf(m1, a1 - c1 + b1);
        }
        acc0 += m0;
        acc1 += m1;
    }
    atomicAdd(&ccsum[n * 512 + half * 256 + cp], acc0);
    atomicAdd(&ccsum[n * 512 + half * 256 + cp + 1], acc1);
}

__global__ __launch_bounds__(256) void se_kernel(const float* __restrict__ ccsum,
                                                 const float* __restrict__ W1,
                                                 const float* __restrict__ b1,
                                                 const float* __restrict__ W2,
                                                 const float* __restrict__ b2,
                                                 float* __restrict__ g) {
    int n = blockIdx.x;
    int t = threadIdx.x;
    __shared__ float hid[16];
    __shared__ float cc[512];
    cc[t] = ccsum[n * 512 + t] * (1.0f / HWT);
    cc[256 + t] = ccsum[n * 512 + 256 + t] * (1.0f / HWT);
    __syncthreads();
    if (t < 16) {
        float s = b1[t];
        for (int j = 0; j < 512; ++j) s = fmaf(W1[t * 512 + j], cc[j], s);
        hid[t] = fmaxf(s, 0.f);
    }
    __syncthreads();
    float s = b2[t];
#pragma unroll
    for (int q = 0; q < 16; ++q) s = fmaf(W2[t * 16 + q], hid[q], s);
    float se = 1.0f / (1.0f + expf(-s));
    g[n * CH + t] *= se;
}

__global__ void final_kernel(const float* __restrict__ cnn, const float* __restrict__ g,
                             const float* __restrict__ gamma, float* __restrict__ out) {
    int t = blockIdx.x * blockDim.x + threadIdx.x;
    if (t >= NB * CH * HWT / 4) return;
    int nc = (t * 4) / HWT;
    float4 x = ((const float4*)cnn)[t];
    float s = gamma[0] * g[nc] + 1.0f;
    float4 o;
    o.x = fmaxf(s * x.x, 0.f);
    o.y = fmaxf(s * x.y, 0.f);
    o.z = fmaxf(s * x.z, 0.f);
    o.w = fmaxf(s * x.w, 0.f);
    ((float4*)out)[t] = o;
}

extern "C" void kernel_launch(void* const* d_in, const int* in_sizes, int n_in,
                              void* d_out, int out_size, void* d_ws, size_t ws_size,
                              hipStream_t stream) {
    const float* cnn    = (const float*)d_in[0];
    const float* rgb    = (const float*)d_in[1];
    const float* ir     = (const float*)d_in[2];
    const float* Wg_rgb = (const float*)d_in[3];
    const float* bg_rgb = (const float*)d_in[4];
    const float* Wg_ir  = (const float*)d_in[5];
    const float* bg_ir  = (const float*)d_in[6];
    const float* Wse1   = (const float*)d_in[7];
    const float* bse1   = (const float*)d_in[8];
    const float* Wse2   = (const float*)d_in[9];
    const float* bse2   = (const float*)d_in[10];
    const float* gamma  = (const float*)d_in[11];
    float* out = (float*)d_out;

    char* ws = (char*)d_ws;
    size_t off = 0;
    float* xpack = (float*)(ws + off); off += (size_t)2 * NB * HWT * 8 * 4;
    int* knn_rgb = (int*)(ws + off); off += (size_t)NB * HWT * KNN * 4;
    int* knn_ir  = (int*)(ws + off); off += (size_t)NB * HWT * KNN * 4;
    float* Wcomb = (float*)(ws + off); off += (size_t)1024 * 256 * 4;
    __hip_bfloat16* Wbf = (__hip_bfloat16*)(ws + off); off += (size_t)NB * 1024 * CH * 2;
    __hip_bfloat16* Abf = (__hip_bfloat16*)(ws + off); off += (size_t)NB * MPAD * CH * 2;
    __hip_bfloat16* Yall = (__hip_bfloat16*)(ws + off); off += (size_t)NB * HWT * 1024 * 2;
    unsigned* partial = (unsigned*)(ws + off);
    off += (size_t)2 * NB * SSEGP * HWT * 8 * 4;     // 14.7 MB
    float* ccsum = (float*)(ws + off); off += (size_t)NB * 512 * 4;
    float* g     = (float*)(ws + off); off += (size_t)NB * CH * 4;

    // prolog: convert_a + Wcomb/Wbf(it0)/g + knn_prep
    fusedA<<<GEMM_BLKS + 1024 + 113, 256, 0, stream>>>(cnn, Abf, Wg_rgb, Wg_ir, Wcomb, g,
                                                       Wbf, rgb, ir, xpack);
    knn_main<<<dim3(SSEGP, 8, 2 * NB), 256, 0, stream>>>(xpack, partial);
    gemm_k<<<GEMM_BLKS, 256, 0, stream>>>(Abf, Wbf, Yall);
    knn_merge_zero<<<458, 256, 0, stream>>>(partial, knn_rgb, knn_ir, ccsum);
    gather_kernel<<<900, 256, 0, stream>>>(Yall, knn_rgb, knn_ir, bg_rgb, bg_ir, ccsum);
    se_kernel<<<NB, 256, 0, stream>>>(ccsum, Wse1, bse1, Wse2, bse2, g);
    // iter 1
    scale_w_zero<<<520, 256, 0, stream>>>(Wcomb, g, Wbf, ccsum);
    gemm_k<<<GEMM_BLKS, 256, 0, stream>>>(Abf, Wbf, Yall);
    gather_kernel<<<900, 256, 0, stream>>>(Yall, knn_rgb, knn_ir, bg_rgb, bg_ir, ccsum);
    se_kernel<<<NB, 256, 0, stream>>>(ccsum, Wse1, bse1, Wse2, bse2, g);
    final_kernel<<<3600, 256, 0, stream>>>(cnn, g, gamma, out);
}

// Round 14
// 209.636 us; speedup vs baseline: 1.2266x; 1.0804x over previous
//
#include <hip/hip_runtime.h>
#include <hip/hip_bf16.h>

#define NB 4
#define CH 256
#define HWT 3600
#define KNN 8
#define POSB 16
#define MPAD 3712

#define SSEGP 16     // knn segments (225 candidates each)
#define CAND 225
#define RROWS 512    // rows per block: 256 threads x 2

#define GEMM_BLKS 928     // 232 * NB

typedef __attribute__((ext_vector_type(8))) __bf16 bf16x8;
typedef __attribute__((ext_vector_type(4))) float f32x4;
typedef __attribute__((ext_vector_type(4))) unsigned u32x4;

__device__ inline float med3f(float a, float b, float c) {
    return __builtin_amdgcn_fmed3f(a, b, c);
}

__device__ __forceinline__ void insert8(float* best, float kf) {
    best[7] = med3f(best[6], best[7], kf);
    best[6] = med3f(best[5], best[6], kf);
    best[5] = med3f(best[4], best[5], kf);
    best[4] = med3f(best[3], best[4], kf);
    best[3] = med3f(best[2], best[3], kf);
    best[2] = med3f(best[1], best[2], kf);
    best[1] = med3f(best[0], best[1], kf);
    best[0] = fminf(best[0], kf);
}

// ================= gemm body =================

__device__ __forceinline__ void gemm_body(int lid, int n,
                                          const __hip_bfloat16* __restrict__ Abf,
                                          const __hip_bfloat16* __restrict__ Wbf,
                                          __hip_bfloat16* __restrict__ Yall,
                                          char* smem) {
    char* sA = smem;
    char* sB = smem + 16384;
    int w = (lid & 7) * 29 + (lid >> 3);
    int m0 = (w >> 3) * 128;
    int o0 = (w & 7) * 128;
    int t = threadIdx.x;
    int lane = t & 63, wid = t >> 6;
    int wm = wid >> 1, wo = wid & 1;

    const __hip_bfloat16* Ab = Abf + (size_t)n * MPAD * CH;
    const __hip_bfloat16* Wb = Wbf + (size_t)n * 1024 * CH;

    f32x4 acc[4][4] = {};

    int srow = t >> 3;
    int sslot = t & 7;
    int swz = (sslot ^ (srow & 7)) << 4;
    int fr = lane & 15;
    int kg = lane >> 4;
    int p = lane & 7;

    uint4 av[4], bv[4];
    auto load_tile = [&](int ks) {
#pragma unroll
        for (int r = 0; r < 4; ++r) {
            int row = srow + 32 * r;
            av[r] = *(const uint4*)(Ab + ((size_t)(m0 + row)) * CH + ks * 64 + sslot * 8);
            bv[r] = *(const uint4*)(Wb + ((size_t)(o0 + row)) * CH + ks * 64 + sslot * 8);
        }
    };
    load_tile(0);

    for (int ks = 0; ks < 4; ++ks) {
        __syncthreads();
#pragma unroll
        for (int r = 0; r < 4; ++r) {
            int row = srow + 32 * r;
            *(uint4*)(sA + row * 128 + swz) = av[r];
            *(uint4*)(sB + row * 128 + swz) = bv[r];
        }
        __syncthreads();
        if (ks < 3) load_tile(ks + 1);
#pragma unroll
        for (int kk = 0; kk < 2; ++kk) {
            bf16x8 hf[4], wf[4];
            int slot = kk * 4 + kg;
            int inrow = (slot ^ p) << 4;
#pragma unroll
            for (int f = 0; f < 4; ++f) {
                hf[f] = *(const bf16x8*)(sA + (wm * 64 + f * 16 + fr) * 128 + inrow);
                wf[f] = *(const bf16x8*)(sB + (wo * 64 + f * 16 + fr) * 128 + inrow);
            }
#pragma unroll
            for (int fa = 0; fa < 4; ++fa)
#pragma unroll
                for (int fb = 0; fb < 4; ++fb)
                    acc[fa][fb] = __builtin_amdgcn_mfma_f32_16x16x32_bf16(
                        wf[fa], hf[fb], acc[fa][fb], 0, 0, 0);
        }
    }

    __syncthreads();
#pragma unroll
    for (int fa = 0; fa < 4; ++fa)
#pragma unroll
        for (int fb = 0; fb < 4; ++fb) {
            int ml = wm * 64 + fb * 16 + fr;
            int ob = (wo * 64 + fa * 16 + kg * 4) * 2;
            f32x4 v = acc[fa][fb];
            union { ushort4 u; __hip_bfloat16 h[4]; } pk;
            pk.h[0] = __float2bfloat16(v.x);
            pk.h[1] = __float2bfloat16(v.y);
            pk.h[2] = __float2bfloat16(v.z);
            pk.h[3] = __float2bfloat16(v.w);
            int swzb = (ob & ~15) ^ ((ml & 15) << 4);
            *(ushort4*)(smem + ml * 256 + swzb + (ob & 15)) = pk.u;
        }
    __syncthreads();
    __hip_bfloat16* Y = Yall + (size_t)n * HWT * 1024;
    int colb = (t & 15) * 16;
#pragma unroll
    for (int i = 0; i < 8; ++i) {
        int row = i * 16 + (t >> 4);
        int grow = m0 + row;
        if (grow < HWT) {
            u32x4 v = *(const u32x4*)(smem + row * 256 + (colb ^ ((row & 15) << 4)));
            __builtin_nontemporal_store(v, (u32x4*)((char*)Y + (size_t)grow * 2048 + o0 * 2 + colb));
        }
    }
}

__global__ __launch_bounds__(256) void gemm_k(const __hip_bfloat16* __restrict__ Abf,
                                              const __hip_bfloat16* __restrict__ Wbf,
                                              __hip_bfloat16* __restrict__ Yall) {
    __shared__ char smem[32768];
    int gid = blockIdx.x;
    gemm_body(gid % 232, gid / 232, Abf, Wbf, Yall, smem);
}

// ================= kNN main v6 (round-13, kept) =================
__global__ __launch_bounds__(256) void knn_main(const float* __restrict__ xpack,
                                                unsigned* __restrict__ partial) {
    int seg = blockIdx.x, rb = blockIdx.y, nm = blockIdx.z;
    int t = threadIdx.x;
    const float* xp = xpack + (size_t)nm * HWT * 8;
    __shared__ float4 xs4[CAND];     // -2 * x_j (dims 0..3)
    __shared__ float2 xs2[CAND];     // {-2 * x4_j, q_j}
    int j0 = seg * CAND;
    if (t < CAND) {
        float4 a = ((const float4*)xp)[(size_t)(j0 + t) * 2];
        float4 b = ((const float4*)xp)[(size_t)(j0 + t) * 2 + 1];
        xs4[t] = float4{-2.f * a.x, -2.f * a.y, -2.f * a.z, -2.f * a.w};
        xs2[t] = float2{-2.f * b.x, b.y};
    }
    __syncthreads();

    int r0 = rb * RROWS + t;
    int r1 = r0 + 256;
    bool act0 = (r0 < HWT);
    bool act1 = (r1 < HWT);
    int rr0 = act0 ? r0 : 0;
    int rr1 = act1 ? r1 : 0;
    float4 a0 = ((const float4*)xp)[(size_t)rr0 * 2];
    float4 b0 = ((const float4*)xp)[(size_t)rr0 * 2 + 1];
    float4 a1 = ((const float4*)xp)[(size_t)rr1 * 2];
    float4 b1 = ((const float4*)xp)[(size_t)rr1 * 2 + 1];
    float rq0 = b0.y + 1.0f, rq1 = b1.y + 1.0f;

    const float BIG = __uint_as_float(0x7F000000u);
    float bst0[8], bst1[8];
#pragma unroll
    for (int i = 0; i < 8; ++i) { bst0[i] = BIG; bst1[i] = BIG; }

    unsigned jg0 = (unsigned)j0;
#pragma unroll 5
    for (int jj = 0; jj < CAND; ++jj) {
        float4 a = xs4[jj];
        float2 b = xs2[jj];
        unsigned jg = jg0 + jj;
        float d0 = fmaf(a.x, a0.x, rq0);
        d0 = fmaf(a.y, a0.y, d0);
        d0 = fmaf(a.z, a0.z, d0);
        d0 = fmaf(a.w, a0.w, d0);
        d0 = fmaf(b.x, b0.x, d0);
        float e0 = d0 + b.y;
        float d1 = fmaf(a.x, a1.x, rq1);
        d1 = fmaf(a.y, a1.y, d1);
        d1 = fmaf(a.z, a1.z, d1);
        d1 = fmaf(a.w, a1.w, d1);
        d1 = fmaf(b.x, b1.x, d1);
        float e1 = d1 + b.y;
        float k0 = __uint_as_float((__float_as_uint(e0) & 0xFFFFF000u) | jg);
        float k1 = __uint_as_float((__float_as_uint(e1) & 0xFFFFF000u) | jg);
        insert8(bst0, k0);
        insert8(bst1, k1);
    }
    if (act0) {
        unsigned* o = partial + (((size_t)(nm * SSEGP + seg)) * HWT + r0) * 8;
        ((uint4*)o)[0] = uint4{ __float_as_uint(bst0[0]), __float_as_uint(bst0[1]),
                                __float_as_uint(bst0[2]), __float_as_uint(bst0[3]) };
        ((uint4*)o)[1] = uint4{ __float_as_uint(bst0[4]), __float_as_uint(bst0[5]),
                                __float_as_uint(bst0[6]), __float_as_uint(bst0[7]) };
    }
    if (act1) {
        unsigned* o1 = partial + (((size_t)(nm * SSEGP + seg)) * HWT + r1) * 8;
        ((uint4*)o1)[0] = uint4{ __float_as_uint(bst1[0]), __float_as_uint(bst1[1]),
                                 __float_as_uint(bst1[2]), __float_as_uint(bst1[3]) };
        ((uint4*)o1)[1] = uint4{ __float_as_uint(bst1[4]), __float_as_uint(bst1[5]),
                                 __float_as_uint(bst1[6]), __float_as_uint(bst1[7]) };
    }
}

// ================= fusedA prolog =================
__global__ __launch_bounds__(256) void fusedA(const float* __restrict__ cnn,
                                              __hip_bfloat16* __restrict__ Abf,
                                              const float* __restrict__ Wg_rgb,
                                              const float* __restrict__ Wg_ir,
                                              float* __restrict__ Wcomb,
                                              float* __restrict__ g,
                                              __hip_bfloat16* __restrict__ Wbf,
                                              const float* __restrict__ rgb,
                                              const float* __restrict__ ir,
                                              float* __restrict__ xpack) {
    int bid = blockIdx.x;
    int t = threadIdx.x;
    if (bid < GEMM_BLKS) {
        __shared__ float st[64][65];
        int n = bid / 232;
        int rem = bid - n * 232;
        int k0 = (rem / 58) * 64;
        int m0 = (rem % 58) * 64;
        const float* src = cnn + (size_t)n * CH * HWT;
#pragma unroll
        for (int r = 0; r < 4; ++r) {
            int kl = r * 16 + (t >> 4);
            int ms = (t & 15) * 4;
            float4 v = {0.f, 0.f, 0.f, 0.f};
            if (m0 + ms < HWT) v = *(const float4*)(src + (size_t)(k0 + kl) * HWT + m0 + ms);
            st[ms + 0][kl] = v.x; st[ms + 1][kl] = v.y;
            st[ms + 2][kl] = v.z; st[ms + 3][kl] = v.w;
        }
        __syncthreads();
        int m = t >> 2, kg = (t & 3) * 16;
        union { uint4 u[2]; __hip_bfloat16 h[16]; } pk;
#pragma unroll
        for (int i = 0; i < 16; ++i) pk.h[i] = __float2bfloat16(st[m][kg + i]);
        __hip_bfloat16* dst = Abf + ((size_t)n * MPAD + m0 + m) * CH + k0 + kg;
        ((uint4*)dst)[0] = pk.u[0];
        ((uint4*)dst)[1] = pk.u[1];
    } else if (bid < GEMM_BLKS + 1024) {
        int e = (bid - GEMM_BLKS) * 256 + t;
        int o = e >> 8, j = e & 255;
        float v;
        if (o < 256)      v = Wg_rgb[o * 512 + j] + Wg_rgb[o * 512 + 256 + j];
        else if (o < 512) v = Wg_rgb[(o - 256) * 512 + 256 + j];
        else if (o < 768) v = Wg_ir[(o - 512) * 512 + j] + Wg_ir[(o - 512) * 512 + 256 + j];
        else              v = Wg_ir[(o - 768) * 512 + 256 + j];
        Wcomb[e] = v;
        __hip_bfloat16 h = __float2bfloat16(v);   // iter0: g == 1
#pragma unroll
        for (int n = 0; n < NB; ++n) Wbf[(size_t)n * 262144 + e] = h;
        if (e < NB * CH) g[e] = 1.0f;
    } else {
        int e = (bid - GEMM_BLKS - 1024) * 256 + t;
        if (e < 2 * NB * HWT) {
            int nm = e / HWT, j = e - nm * HWT;
            int mod = nm / NB, n = nm - mod * NB;
            const float* x = (mod == 0 ? rgb : ir) + (size_t)n * 5 * HWT;
            float v[5], q = 0.f;
#pragma unroll
            for (int d = 0; d < 5; ++d) { v[d] = x[d * HWT + j]; q = fmaf(v[d], v[d], q); }
            float* o = xpack + (size_t)e * 8;
#pragma unroll
            for (int d = 0; d < 5; ++d) o[d] = v[d];
            o[5] = q; o[6] = 0.f; o[7] = 0.f;
        }
    }
}

// ================= merge + zero =================
__global__ __launch_bounds__(256) void knn_merge_zero(const unsigned* __restrict__ partial,
                                                      int* __restrict__ knn_rgb,
                                                      int* __restrict__ knn_ir,
                                                      float* __restrict__ ccsum) {
    int bid = blockIdx.x;
    if (bid >= 450) {
        int e = (bid - 450) * 256 + threadIdx.x;
        if (e < NB * 512) ccsum[e] = 0.f;
        return;
    }
    int tid = bid * 256 + threadIdx.x;
    int rid = tid >> 1, sub = tid & 1;
    int nm = rid / HWT, row = rid - nm * HWT;
    const float BIG = __uint_as_float(0x7F000000u);
    float best[8];
#pragma unroll
    for (int i = 0; i < 8; ++i) best[i] = BIG;
    for (int s = sub; s < SSEGP; s += 2) {
        const unsigned* p = partial + (((size_t)(nm * SSEGP + s)) * HWT + row) * 8;
#pragma unroll
        for (int w = 0; w < 2; ++w) {
            uint4 v = ((const uint4*)p)[w];
            unsigned vv[4] = { v.x, v.y, v.z, v.w };
#pragma unroll
            for (int e = 0; e < 4; ++e) insert8(best, __uint_as_float(vv[e]));
        }
    }
    float other[8];
#pragma unroll
    for (int i = 0; i < 8; ++i) other[i] = __shfl_xor(best[i], 1);
#pragma unroll
    for (int i = 0; i < 8; ++i) insert8(best, other[i]);
    if (sub == 0) {
        int mod = nm / NB, n = nm - mod * NB;
        int* o = (mod == 0 ? knn_rgb : knn_ir) + ((size_t)n * HWT + row) * KNN;
#pragma unroll
        for (int i = 0; i < 8; ++i) o[i] = (int)(__float_as_uint(best[i]) & 0xFFFu);
    }
}

// ================= scale_w + zero =================
__global__ __launch_bounds__(256) void scale_w_zero(const float* __restrict__ Wcomb,
                                                    const float* __restrict__ g,
                                                    __hip_bfloat16* __restrict__ Wbf,
                                                    float* __restrict__ ccsum) {
    int bid = blockIdx.x;
    if (bid >= 512) {
        int e = (bid - 512) * 256 + threadIdx.x;
        if (e < NB * 512) ccsum[e] = 0.f;
        return;
    }
    int n = bid >> 7;
    int gid = (bid & 127) * 256 + threadIdx.x;
    int o = gid >> 5;
    int kb = (gid & 31) * 8;
    const float* w = Wcomb + o * 256 + kb;
    const float* gp = g + n * CH + kb;
    union { uint4 u; __hip_bfloat16 h[8]; } pk;
#pragma unroll
    for (int i = 0; i < 8; ++i) pk.h[i] = __float2bfloat16(w[i] * gp[i]);
    *(uint4*)(Wbf + ((size_t)n * 1024 + o) * CH + kb) = pk.u;
}

// ================= gather: XCD-pinned channel-slice groups =================
// grid 3600; g = lid & 15 -> XCD = g&7 (round-robin): each XCD's Y working set
// = 2 batches x (A-slice + B-slice) = 3.6 MB < 4 MB L2.
// g bits: [3]=n_low, [2]=n_high, [1]=mod, [0]=chalf. sub = lid>>4 (0..224).
__global__ __launch_bounds__(256) void gather_kernel(const __hip_bfloat16* __restrict__ Yall,
                                                     const int* __restrict__ knn_rgb,
                                                     const int* __restrict__ knn_ir,
                                                     const float* __restrict__ b_rgb,
                                                     const float* __restrict__ b_ir,
                                                     float* __restrict__ ccsum) {
    int lid = blockIdx.x;
    int grp = lid & 15, sub = lid >> 4;
    int n = ((grp >> 3) & 1) | (((grp >> 2) & 1) << 1);
    int mod = (grp >> 1) & 1;
    int chalf = grp & 1;
    int hwbase = sub * 16;
    int t = threadIdx.x;
    int psub = t >> 6;                    // 0..3, 4 positions each
    int pr = t & 63;                      // channel-pair
    int cp = chalf * 128 + pr * 2;
    __shared__ int sidx[16][2][KNN];
    __shared__ float red[4][64][2];
    {
        int p = t >> 4, rem = t & 15;
        int hw = hwbase + p;
        int v;
        if (rem < 8) v = knn_rgb[((size_t)n * HWT + hw) * KNN + rem];
        else         v = knn_ir[((size_t)n * HWT + hw) * KNN + (rem - 8)];
        sidx[p][rem >> 3][rem & 7] = v;
    }
    __syncthreads();
    const float* bias = mod ? b_ir : b_rgb;
    float b0 = bias[cp], b1 = bias[cp + 1];
    float acc0 = 0.f, acc1 = 0.f;
    const __hip_bfloat16* Y = Yall + (size_t)n * HWT * 1024;
    int offA = mod * 512 + cp;
    int offB = mod * 512 + 256 + cp;
    for (int p = psub * 4; p < psub * 4 + 4; ++p) {
        float m0 = 0.f, m1 = 0.f;
#pragma unroll
        for (int k = 0; k < KNN; ++k) {
            int jA = sidx[p][mod][k];
            int jB = sidx[p][mod ^ 1][k];
            unsigned u1 = *(const unsigned*)(Y + (size_t)jA * 1024 + offA);
            unsigned u2 = *(const unsigned*)(Y + (size_t)jB * 1024 + offB);
            float a0 = __uint_as_float(u1 << 16);
            float a1 = __uint_as_float(u1 & 0xFFFF0000u);
            float c0 = __uint_as_float(u2 << 16);
            float c1 = __uint_as_float(u2 & 0xFFFF0000u);
            m0 = fmaxf(m0, a0 - c0 + b0);
            m1 = fmaxf(m1, a1 - c1 + b1);
        }
        acc0 += m0;
        acc1 += m1;
    }
    if (psub) { red[psub][pr][0] = acc0; red[psub][pr][1] = acc1; }
    __syncthreads();
    if (psub == 0) {
#pragma unroll
        for (int q = 1; q < 4; ++q) {
            acc0 += red[q][pr][0];
            acc1 += red[q][pr][1];
        }
        atomicAdd(&ccsum[n * 512 + mod * 256 + cp], acc0);
        atomicAdd(&ccsum[n * 512 + mod * 256 + cp + 1], acc1);
    }
}

__global__ __launch_bounds__(256) void se_kernel(const float* __restrict__ ccsum,
                                                 const float* __restrict__ W1,
                                                 const float* __restrict__ b1,
                                                 const float* __restrict__ W2,
                                                 const float* __restrict__ b2,
                                                 float* __restrict__ g) {
    int n = blockIdx.x;
    int t = threadIdx.x;
    __shared__ float hid[16];
    __shared__ float cc[512];
    cc[t] = ccsum[n * 512 + t] * (1.0f / HWT);
    cc[256 + t] = ccsum[n * 512 + 256 + t] * (1.0f / HWT);
    __syncthreads();
    if (t < 16) {
        float s = b1[t];
        for (int j = 0; j < 512; ++j) s = fmaf(W1[t * 512 + j], cc[j], s);
        hid[t] = fmaxf(s, 0.f);
    }
    __syncthreads();
    float s = b2[t];
#pragma unroll
    for (int q = 0; q < 16; ++q) s = fmaf(W2[t * 16 + q], hid[q], s);
    float se = 1.0f / (1.0f + expf(-s));
    g[n * CH + t] *= se;
}

__global__ void final_kernel(const float* __restrict__ cnn, const float* __restrict__ g,
                             const float* __restrict__ gamma, float* __restrict__ out) {
    int t = blockIdx.x * blockDim.x + threadIdx.x;
    if (t >= NB * CH * HWT / 4) return;
    int nc = (t * 4) / HWT;
    float4 x = ((const float4*)cnn)[t];
    float s = gamma[0] * g[nc] + 1.0f;
    float4 o;
    o.x = fmaxf(s * x.x, 0.f);
    o.y = fmaxf(s * x.y, 0.f);
    o.z = fmaxf(s * x.z, 0.f);
    o.w = fmaxf(s * x.w, 0.f);
    ((float4*)out)[t] = o;
}

extern "C" void kernel_launch(void* const* d_in, const int* in_sizes, int n_in,
                              void* d_out, int out_size, void* d_ws, size_t ws_size,
                              hipStream_t stream) {
    const float* cnn    = (const float*)d_in[0];
    const float* rgb    = (const float*)d_in[1];
    const float* ir     = (const float*)d_in[2];
    const float* Wg_rgb = (const float*)d_in[3];
    const float* bg_rgb = (const float*)d_in[4];
    const float* Wg_ir  = (const float*)d_in[5];
    const float* bg_ir  = (const float*)d_in[6];
    const float* Wse1   = (const float*)d_in[7];
    const float* bse1   = (const float*)d_in[8];
    const float* Wse2   = (const float*)d_in[9];
    const float* bse2   = (const float*)d_in[10];
    const float* gamma  = (const float*)d_in[11];
    float* out = (float*)d_out;

    char* ws = (char*)d_ws;
    size_t off = 0;
    float* xpack = (float*)(ws + off); off += (size_t)2 * NB * HWT * 8 * 4;
    int* knn_rgb = (int*)(ws + off); off += (size_t)NB * HWT * KNN * 4;
    int* knn_ir  = (int*)(ws + off); off += (size_t)NB * HWT * KNN * 4;
    float* Wcomb = (float*)(ws + off); off += (size_t)1024 * 256 * 4;
    __hip_bfloat16* Wbf = (__hip_bfloat16*)(ws + off); off += (size_t)NB * 1024 * CH * 2;
    __hip_bfloat16* Abf = (__hip_bfloat16*)(ws + off); off += (size_t)NB * MPAD * CH * 2;
    __hip_bfloat16* Yall = (__hip_bfloat16*)(ws + off); off += (size_t)NB * HWT * 1024 * 2;
    unsigned* partial = (unsigned*)(ws + off);
    off += (size_t)2 * NB * SSEGP * HWT * 8 * 4;     // 14.7 MB
    float* ccsum = (float*)(ws + off); off += (size_t)NB * 512 * 4;
    float* g     = (float*)(ws + off); off += (size_t)NB * CH * 4;

    // prolog: convert_a + Wcomb/Wbf(it0)/g + knn_prep
    fusedA<<<GEMM_BLKS + 1024 + 113, 256, 0, stream>>>(cnn, Abf, Wg_rgb, Wg_ir, Wcomb, g,
                                                       Wbf, rgb, ir, xpack);
    knn_main<<<dim3(SSEGP, 8, 2 * NB), 256, 0, stream>>>(xpack, partial);
    gemm_k<<<GEMM_BLKS, 256, 0, stream>>>(Abf, Wbf, Yall);
    knn_merge_zero<<<458, 256, 0, stream>>>(partial, knn_rgb, knn_ir, ccsum);
    gather_kernel<<<3600, 256, 0, stream>>>(Yall, knn_rgb, knn_ir, bg_rgb, bg_ir, ccsum);
    se_kernel<<<NB, 256, 0, stream>>>(ccsum, Wse1, bse1, Wse2, bse2, g);
    // iter 1
    scale_w_zero<<<520, 256, 0, stream>>>(Wcomb, g, Wbf, ccsum);
    gemm_k<<<GEMM_BLKS, 256, 0, stream>>>(Abf, Wbf, Yall);
    gather_kernel<<<3600, 256, 0, stream>>>(Yall, knn_rgb, knn_ir, bg_rgb, bg_ir, ccsum);
    se_kernel<<<NB, 256, 0, stream>>>(ccsum, Wse1, bse1, Wse2, bse2, g);
    final_kernel<<<3600, 256, 0, stream>>>(cnn, g, gamma, out);
}

// Round 15
// 208.497 us; speedup vs baseline: 1.2333x; 1.0055x over previous
//
#include <hip/hip_runtime.h>
#include <hip/hip_bf16.h>

#define NB 4
#define CH 256
#define HWT 3600
#define KNN 8
#define POSB 16
#define MPAD 3712

#define SSEGP 16     // knn segments (225 candidates each)
#define CAND 225
#define RROWS 512    // rows per block: 256 threads x 2

#define GEMM_BLKS 928     // 232 * NB

typedef __attribute__((ext_vector_type(8))) __bf16 bf16x8;
typedef __attribute__((ext_vector_type(4))) float f32x4;
typedef __attribute__((ext_vector_type(4))) unsigned u32x4;

__device__ inline float med3f(float a, float b, float c) {
    return __builtin_amdgcn_fmed3f(a, b, c);
}

__device__ __forceinline__ void insert8(float* best, float kf) {
    best[7] = med3f(best[6], best[7], kf);
    best[6] = med3f(best[5], best[6], kf);
    best[5] = med3f(best[4], best[5], kf);
    best[4] = med3f(best[3], best[4], kf);
    best[3] = med3f(best[2], best[3], kf);
    best[2] = med3f(best[1], best[2], kf);
    best[1] = med3f(best[0], best[1], kf);
    best[0] = fminf(best[0], kf);
}

// ================= gemm body =================

__device__ __forceinline__ void gemm_body(int lid, int n,
                                          const __hip_bfloat16* __restrict__ Abf,
                                          const __hip_bfloat16* __restrict__ Wbf,
                                          __hip_bfloat16* __restrict__ Yall,
                                          char* smem) {
    char* sA = smem;
    char* sB = smem + 16384;
    int w = (lid & 7) * 29 + (lid >> 3);
    int m0 = (w >> 3) * 128;
    int o0 = (w & 7) * 128;
    int t = threadIdx.x;
    int lane = t & 63, wid = t >> 6;
    int wm = wid >> 1, wo = wid & 1;

    const __hip_bfloat16* Ab = Abf + (size_t)n * MPAD * CH;
    const __hip_bfloat16* Wb = Wbf + (size_t)n * 1024 * CH;

    f32x4 acc[4][4] = {};

    int srow = t >> 3;
    int sslot = t & 7;
    int swz = (sslot ^ (srow & 7)) << 4;
    int fr = lane & 15;
    int kg = lane >> 4;
    int p = lane & 7;

    uint4 av[4], bv[4];
    auto load_tile = [&](int ks) {
#pragma unroll
        for (int r = 0; r < 4; ++r) {
            int row = srow + 32 * r;
            av[r] = *(const uint4*)(Ab + ((size_t)(m0 + row)) * CH + ks * 64 + sslot * 8);
            bv[r] = *(const uint4*)(Wb + ((size_t)(o0 + row)) * CH + ks * 64 + sslot * 8);
        }
    };
    load_tile(0);

    for (int ks = 0; ks < 4; ++ks) {
        __syncthreads();
#pragma unroll
        for (int r = 0; r < 4; ++r) {
            int row = srow + 32 * r;
            *(uint4*)(sA + row * 128 + swz) = av[r];
            *(uint4*)(sB + row * 128 + swz) = bv[r];
        }
        __syncthreads();
        if (ks < 3) load_tile(ks + 1);
#pragma unroll
        for (int kk = 0; kk < 2; ++kk) {
            bf16x8 hf[4], wf[4];
            int slot = kk * 4 + kg;
            int inrow = (slot ^ p) << 4;
#pragma unroll
            for (int f = 0; f < 4; ++f) {
                hf[f] = *(const bf16x8*)(sA + (wm * 64 + f * 16 + fr) * 128 + inrow);
                wf[f] = *(const bf16x8*)(sB + (wo * 64 + f * 16 + fr) * 128 + inrow);
            }
#pragma unroll
            for (int fa = 0; fa < 4; ++fa)
#pragma unroll
                for (int fb = 0; fb < 4; ++fb)
                    acc[fa][fb] = __builtin_amdgcn_mfma_f32_16x16x32_bf16(
                        wf[fa], hf[fb], acc[fa][fb], 0, 0, 0);
        }
    }

    __syncthreads();
#pragma unroll
    for (int fa = 0; fa < 4; ++fa)
#pragma unroll
        for (int fb = 0; fb < 4; ++fb) {
            int ml = wm * 64 + fb * 16 + fr;
            int ob = (wo * 64 + fa * 16 + kg * 4) * 2;
            f32x4 v = acc[fa][fb];
            union { ushort4 u; __hip_bfloat16 h[4]; } pk;
            pk.h[0] = __float2bfloat16(v.x);
            pk.h[1] = __float2bfloat16(v.y);
            pk.h[2] = __float2bfloat16(v.z);
            pk.h[3] = __float2bfloat16(v.w);
            int swzb = (ob & ~15) ^ ((ml & 15) << 4);
            *(ushort4*)(smem + ml * 256 + swzb + (ob & 15)) = pk.u;
        }
    __syncthreads();
    __hip_bfloat16* Y = Yall + (size_t)n * HWT * 1024;
    int colb = (t & 15) * 16;
#pragma unroll
    for (int i = 0; i < 8; ++i) {
        int row = i * 16 + (t >> 4);
        int grow = m0 + row;
        if (grow < HWT) {
            u32x4 v = *(const u32x4*)(smem + row * 256 + (colb ^ ((row & 15) << 4)));
            __builtin_nontemporal_store(v, (u32x4*)((char*)Y + (size_t)grow * 2048 + o0 * 2 + colb));
        }
    }
}

__global__ __launch_bounds__(256) void gemm_k(const __hip_bfloat16* __restrict__ Abf,
                                              const __hip_bfloat16* __restrict__ Wbf,
                                              __hip_bfloat16* __restrict__ Yall) {
    __shared__ char smem[32768];
    int gid = blockIdx.x;
    gemm_body(gid % 232, gid / 232, Abf, Wbf, Yall, smem);
}

// ================= kNN main v7: no LDS — wave-uniform scalar reads of candidates =================
// grid (16, 8, 2*NB) = 1024 blocks; block: 256 threads x 2 rows x 225 cand
__global__ __launch_bounds__(256) void knn_main(const float* __restrict__ xpack,
                                                unsigned* __restrict__ partial) {
    int seg = blockIdx.x, rb = blockIdx.y, nm = blockIdx.z;
    int t = threadIdx.x;
    const float* xp = xpack + (size_t)nm * HWT * 8;
    int j0 = seg * CAND;

    int r0 = rb * RROWS + t;                // rows r0 and r0+256
    int r1 = r0 + 256;
    bool act0 = (r0 < HWT);
    bool act1 = (r1 < HWT);
    int rr0 = act0 ? r0 : 0;
    int rr1 = act1 ? r1 : 0;
    float4 a0 = ((const float4*)xp)[(size_t)rr0 * 2];
    float4 b0 = ((const float4*)xp)[(size_t)rr0 * 2 + 1];
    float4 a1 = ((const float4*)xp)[(size_t)rr1 * 2];
    float4 b1 = ((const float4*)xp)[(size_t)rr1 * 2 + 1];
    // fold the -2 into the per-thread row registers (keys bit-identical to v6)
    float s00 = -2.f * a0.x, s01 = -2.f * a0.y, s02 = -2.f * a0.z, s03 = -2.f * a0.w;
    float s04 = -2.f * b0.x;
    float s10 = -2.f * a1.x, s11 = -2.f * a1.y, s12 = -2.f * a1.z, s13 = -2.f * a1.w;
    float s14 = -2.f * b1.x;
    float rq0 = b0.y + 1.0f, rq1 = b1.y + 1.0f;   // q_i + 1 per row

    const float BIG = __uint_as_float(0x7F000000u);
    float bst0[8], bst1[8];
#pragma unroll
    for (int i = 0; i < 8; ++i) { bst0[i] = BIG; bst1[i] = BIG; }

    // candidate pointer is block-uniform -> compiler emits scalar (s_load) reads
    const float* cp = xp + (size_t)j0 * 8;
    unsigned jg0 = (unsigned)j0;
#pragma unroll 5
    for (int jj = 0; jj < CAND; ++jj) {
        float c0 = cp[0], c1 = cp[1], c2 = cp[2], c3 = cp[3], c4 = cp[4], cq = cp[5];
        cp += 8;
        unsigned jg = jg0 + jj;
        // row 0: e = (q_i+1) - 2*dot + q_j
        float d0 = fmaf(c0, s00, rq0);
        d0 = fmaf(c1, s01, d0);
        d0 = fmaf(c2, s02, d0);
        d0 = fmaf(c3, s03, d0);
        d0 = fmaf(c4, s04, d0);
        float e0 = d0 + cq;
        // row 1
        float d1 = fmaf(c0, s10, rq1);
        d1 = fmaf(c1, s11, d1);
        d1 = fmaf(c2, s12, d1);
        d1 = fmaf(c3, s13, d1);
        d1 = fmaf(c4, s14, d1);
        float e1 = d1 + cq;
        float k0 = __uint_as_float((__float_as_uint(e0) & 0xFFFFF000u) | jg);
        float k1 = __uint_as_float((__float_as_uint(e1) & 0xFFFFF000u) | jg);
        insert8(bst0, k0);
        insert8(bst1, k1);
    }
    if (act0) {
        unsigned* o = partial + (((size_t)(nm * SSEGP + seg)) * HWT + r0) * 8;
        ((uint4*)o)[0] = uint4{ __float_as_uint(bst0[0]), __float_as_uint(bst0[1]),
                                __float_as_uint(bst0[2]), __float_as_uint(bst0[3]) };
        ((uint4*)o)[1] = uint4{ __float_as_uint(bst0[4]), __float_as_uint(bst0[5]),
                                __float_as_uint(bst0[6]), __float_as_uint(bst0[7]) };
    }
    if (act1) {
        unsigned* o1 = partial + (((size_t)(nm * SSEGP + seg)) * HWT + r1) * 8;
        ((uint4*)o1)[0] = uint4{ __float_as_uint(bst1[0]), __float_as_uint(bst1[1]),
                                 __float_as_uint(bst1[2]), __float_as_uint(bst1[3]) };
        ((uint4*)o1)[1] = uint4{ __float_as_uint(bst1[4]), __float_as_uint(bst1[5]),
                                 __float_as_uint(bst1[6]), __float_as_uint(bst1[7]) };
    }
}

// ================= fusedA prolog =================
__global__ __launch_bounds__(256) void fusedA(const float* __restrict__ cnn,
                                              __hip_bfloat16* __restrict__ Abf,
                                              const float* __restrict__ Wg_rgb,
                                              const float* __restrict__ Wg_ir,
                                              float* __restrict__ Wcomb,
                                              float* __restrict__ g,
                                              __hip_bfloat16* __restrict__ Wbf,
                                              const float* __restrict__ rgb,
                                              const float* __restrict__ ir,
                                              float* __restrict__ xpack) {
    int bid = blockIdx.x;
    int t = threadIdx.x;
    if (bid < GEMM_BLKS) {
        __shared__ float st[64][65];
        int n = bid / 232;
        int rem = bid - n * 232;
        int k0 = (rem / 58) * 64;
        int m0 = (rem % 58) * 64;
        const float* src = cnn + (size_t)n * CH * HWT;
#pragma unroll
        for (int r = 0; r < 4; ++r) {
            int kl = r * 16 + (t >> 4);
            int ms = (t & 15) * 4;
            float4 v = {0.f, 0.f, 0.f, 0.f};
            if (m0 + ms < HWT) v = *(const float4*)(src + (size_t)(k0 + kl) * HWT + m0 + ms);
            st[ms + 0][kl] = v.x; st[ms + 1][kl] = v.y;
            st[ms + 2][kl] = v.z; st[ms + 3][kl] = v.w;
        }
        __syncthreads();
        int m = t >> 2, kg = (t & 3) * 16;
        union { uint4 u[2]; __hip_bfloat16 h[16]; } pk;
#pragma unroll
        for (int i = 0; i < 16; ++i) pk.h[i] = __float2bfloat16(st[m][kg + i]);
        __hip_bfloat16* dst = Abf + ((size_t)n * MPAD + m0 + m) * CH + k0 + kg;
        ((uint4*)dst)[0] = pk.u[0];
        ((uint4*)dst)[1] = pk.u[1];
    } else if (bid < GEMM_BLKS + 1024) {
        int e = (bid - GEMM_BLKS) * 256 + t;
        int o = e >> 8, j = e & 255;
        float v;
        if (o < 256)      v = Wg_rgb[o * 512 + j] + Wg_rgb[o * 512 + 256 + j];
        else if (o < 512) v = Wg_rgb[(o - 256) * 512 + 256 + j];
        else if (o < 768) v = Wg_ir[(o - 512) * 512 + j] + Wg_ir[(o - 512) * 512 + 256 + j];
        else              v = Wg_ir[(o - 768) * 512 + 256 + j];
        Wcomb[e] = v;
        __hip_bfloat16 h = __float2bfloat16(v);   // iter0: g == 1
#pragma unroll
        for (int n = 0; n < NB; ++n) Wbf[(size_t)n * 262144 + e] = h;
        if (e < NB * CH) g[e] = 1.0f;
    } else {
        int e = (bid - GEMM_BLKS - 1024) * 256 + t;
        if (e < 2 * NB * HWT) {
            int nm = e / HWT, j = e - nm * HWT;
            int mod = nm / NB, n = nm - mod * NB;
            const float* x = (mod == 0 ? rgb : ir) + (size_t)n * 5 * HWT;
            float v[5], q = 0.f;
#pragma unroll
            for (int d = 0; d < 5; ++d) { v[d] = x[d * HWT + j]; q = fmaf(v[d], v[d], q); }
            float* o = xpack + (size_t)e * 8;
#pragma unroll
            for (int d = 0; d < 5; ++d) o[d] = v[d];
            o[5] = q; o[6] = 0.f; o[7] = 0.f;
        }
    }
}

// ================= merge + zero =================
__global__ __launch_bounds__(256) void knn_merge_zero(const unsigned* __restrict__ partial,
                                                      int* __restrict__ knn_rgb,
                                                      int* __restrict__ knn_ir,
                                                      float* __restrict__ ccsum) {
    int bid = blockIdx.x;
    if (bid >= 450) {
        int e = (bid - 450) * 256 + threadIdx.x;
        if (e < NB * 512) ccsum[e] = 0.f;
        return;
    }
    int tid = bid * 256 + threadIdx.x;
    int rid = tid >> 1, sub = tid & 1;
    int nm = rid / HWT, row = rid - nm * HWT;
    const float BIG = __uint_as_float(0x7F000000u);
    float best[8];
#pragma unroll
    for (int i = 0; i < 8; ++i) best[i] = BIG;
    for (int s = sub; s < SSEGP; s += 2) {
        const unsigned* p = partial + (((size_t)(nm * SSEGP + s)) * HWT + row) * 8;
#pragma unroll
        for (int w = 0; w < 2; ++w) {
            uint4 v = ((const uint4*)p)[w];
            unsigned vv[4] = { v.x, v.y, v.z, v.w };
#pragma unroll
            for (int e = 0; e < 4; ++e) insert8(best, __uint_as_float(vv[e]));
        }
    }
    float other[8];
#pragma unroll
    for (int i = 0; i < 8; ++i) other[i] = __shfl_xor(best[i], 1);
#pragma unroll
    for (int i = 0; i < 8; ++i) insert8(best, other[i]);
    if (sub == 0) {
        int mod = nm / NB, n = nm - mod * NB;
        int* o = (mod == 0 ? knn_rgb : knn_ir) + ((size_t)n * HWT + row) * KNN;
#pragma unroll
        for (int i = 0; i < 8; ++i) o[i] = (int)(__float_as_uint(best[i]) & 0xFFFu);
    }
}

// ================= scale_w + zero =================
__global__ __launch_bounds__(256) void scale_w_zero(const float* __restrict__ Wcomb,
                                                    const float* __restrict__ g,
                                                    __hip_bfloat16* __restrict__ Wbf,
                                                    float* __restrict__ ccsum) {
    int bid = blockIdx.x;
    if (bid >= 512) {
        int e = (bid - 512) * 256 + threadIdx.x;
        if (e < NB * 512) ccsum[e] = 0.f;
        return;
    }
    int n = bid >> 7;
    int gid = (bid & 127) * 256 + threadIdx.x;
    int o = gid >> 5;
    int kb = (gid & 31) * 8;
    const float* w = Wcomb + o * 256 + kb;
    const float* gp = g + n * CH + kb;
    union { uint4 u; __hip_bfloat16 h[8]; } pk;
#pragma unroll
    for (int i = 0; i < 8; ++i) pk.h[i] = __float2bfloat16(w[i] * gp[i]);
    *(uint4*)(Wbf + ((size_t)n * 1024 + o) * CH + kb) = pk.u;
}

// ================= gather: XCD-pinned channel-slice groups (round-14, kept) =================
__global__ __launch_bounds__(256) void gather_kernel(const __hip_bfloat16* __restrict__ Yall,
                                                     const int* __restrict__ knn_rgb,
                                                     const int* __restrict__ knn_ir,
                                                     const float* __restrict__ b_rgb,
                                                     const float* __restrict__ b_ir,
                                                     float* __restrict__ ccsum) {
    int lid = blockIdx.x;
    int grp = lid & 15, sub = lid >> 4;
    int n = ((grp >> 3) & 1) | (((grp >> 2) & 1) << 1);
    int mod = (grp >> 1) & 1;
    int chalf = grp & 1;
    int hwbase = sub * 16;
    int t = threadIdx.x;
    int psub = t >> 6;
    int pr = t & 63;
    int cp = chalf * 128 + pr * 2;
    __shared__ int sidx[16][2][KNN];
    __shared__ float red[4][64][2];
    {
        int p = t >> 4, rem = t & 15;
        int hw = hwbase + p;
        int v;
        if (rem < 8) v = knn_rgb[((size_t)n * HWT + hw) * KNN + rem];
        else         v = knn_ir[((size_t)n * HWT + hw) * KNN + (rem - 8)];
        sidx[p][rem >> 3][rem & 7] = v;
    }
    __syncthreads();
    const float* bias = mod ? b_ir : b_rgb;
    float b0 = bias[cp], b1 = bias[cp + 1];
    float acc0 = 0.f, acc1 = 0.f;
    const __hip_bfloat16* Y = Yall + (size_t)n * HWT * 1024;
    int offA = mod * 512 + cp;
    int offB = mod * 512 + 256 + cp;
    for (int p = psub * 4; p < psub * 4 + 4; ++p) {
        float m0 = 0.f, m1 = 0.f;
#pragma unroll
        for (int k = 0; k < KNN; ++k) {
            int jA = sidx[p][mod][k];
            int jB = sidx[p][mod ^ 1][k];
            unsigned u1 = *(const unsigned*)(Y + (size_t)jA * 1024 + offA);
            unsigned u2 = *(const unsigned*)(Y + (size_t)jB * 1024 + offB);
            float a0 = __uint_as_float(u1 << 16);
            float a1 = __uint_as_float(u1 & 0xFFFF0000u);
            float c0 = __uint_as_float(u2 << 16);
            float c1 = __uint_as_float(u2 & 0xFFFF0000u);
            m0 = fmaxf(m0, a0 - c0 + b0);
            m1 = fmaxf(m1, a1 - c1 + b1);
        }
        acc0 += m0;
        acc1 += m1;
    }
    if (psub) { red[psub][pr][0] = acc0; red[psub][pr][1] = acc1; }
    __syncthreads();
    if (psub == 0) {
#pragma unroll
        for (int q = 1; q < 4; ++q) {
            acc0 += red[q][pr][0];
            acc1 += red[q][pr][1];
        }
        atomicAdd(&ccsum[n * 512 + mod * 256 + cp], acc0);
        atomicAdd(&ccsum[n * 512 + mod * 256 + cp + 1], acc1);
    }
}

__global__ __launch_bounds__(256) void se_kernel(const float* __restrict__ ccsum,
                                                 const float* __restrict__ W1,
                                                 const float* __restrict__ b1,
                                                 const float* __restrict__ W2,
                                                 const float* __restrict__ b2,
                                                 float* __restrict__ g) {
    int n = blockIdx.x;
    int t = threadIdx.x;
    __shared__ float hid[16];
    __shared__ float cc[512];
    cc[t] = ccsum[n * 512 + t] * (1.0f / HWT);
    cc[256 + t] = ccsum[n * 512 + 256 + t] * (1.0f / HWT);
    __syncthreads();
    if (t < 16) {
        float s = b1[t];
        for (int j = 0; j < 512; ++j) s = fmaf(W1[t * 512 + j], cc[j], s);
        hid[t] = fmaxf(s, 0.f);
    }
    __syncthreads();
    float s = b2[t];
#pragma unroll
    for (int q = 0; q < 16; ++q) s = fmaf(W2[t * 16 + q], hid[q], s);
    float se = 1.0f / (1.0f + expf(-s));
    g[n * CH + t] *= se;
}

__global__ void final_kernel(const float* __restrict__ cnn, const float* __restrict__ g,
                             const float* __restrict__ gamma, float* __restrict__ out) {
    int t = blockIdx.x * blockDim.x + threadIdx.x;
    if (t >= NB * CH * HWT / 4) return;
    int nc = (t * 4) / HWT;
    float4 x = ((const float4*)cnn)[t];
    float s = gamma[0] * g[nc] + 1.0f;
    float4 o;
    o.x = fmaxf(s * x.x, 0.f);
    o.y = fmaxf(s * x.y, 0.f);
    o.z = fmaxf(s * x.z, 0.f);
    o.w = fmaxf(s * x.w, 0.f);
    ((float4*)out)[t] = o;
}

extern "C" void kernel_launch(void* const* d_in, const int* in_sizes, int n_in,
                              void* d_out, int out_size, void* d_ws, size_t ws_size,
                              hipStream_t stream) {
    const float* cnn    = (const float*)d_in[0];
    const float* rgb    = (const float*)d_in[1];
    const float* ir     = (const float*)d_in[2];
    const float* Wg_rgb = (const float*)d_in[3];
    const float* bg_rgb = (const float*)d_in[4];
    const float* Wg_ir  = (const float*)d_in[5];
    const float* bg_ir  = (const float*)d_in[6];
    const float* Wse1   = (const float*)d_in[7];
    const float* bse1   = (const float*)d_in[8];
    const float* Wse2   = (const float*)d_in[9];
    const float* bse2   = (const float*)d_in[10];
    const float* gamma  = (const float*)d_in[11];
    float* out = (float*)d_out;

    char* ws = (char*)d_ws;
    size_t off = 0;
    float* xpack = (float*)(ws + off); off += (size_t)2 * NB * HWT * 8 * 4;
    int* knn_rgb = (int*)(ws + off); off += (size_t)NB * HWT * KNN * 4;
    int* knn_ir  = (int*)(ws + off); off += (size_t)NB * HWT * KNN * 4;
    float* Wcomb = (float*)(ws + off); off += (size_t)1024 * 256 * 4;
    __hip_bfloat16* Wbf = (__hip_bfloat16*)(ws + off); off += (size_t)NB * 1024 * CH * 2;
    __hip_bfloat16* Abf = (__hip_bfloat16*)(ws + off); off += (size_t)NB * MPAD * CH * 2;
    __hip_bfloat16* Yall = (__hip_bfloat16*)(ws + off); off += (size_t)NB * HWT * 1024 * 2;
    unsigned* partial = (unsigned*)(ws + off);
    off += (size_t)2 * NB * SSEGP * HWT * 8 * 4;     // 14.7 MB
    float* ccsum = (float*)(ws + off); off += (size_t)NB * 512 * 4;
    float* g     = (float*)(ws + off); off += (size_t)NB * CH * 4;

    // prolog: convert_a + Wcomb/Wbf(it0)/g + knn_prep
    fusedA<<<GEMM_BLKS + 1024 + 113, 256, 0, stream>>>(cnn, Abf, Wg_rgb, Wg_ir, Wcomb, g,
                                                       Wbf, rgb, ir, xpack);
    knn_main<<<dim3(SSEGP, 8, 2 * NB), 256, 0, stream>>>(xpack, partial);
    gemm_k<<<GEMM_BLKS, 256, 0, stream>>>(Abf, Wbf, Yall);
    knn_merge_zero<<<458, 256, 0, stream>>>(partial, knn_rgb, knn_ir, ccsum);
    gather_kernel<<<3600, 256, 0, stream>>>(Yall, knn_rgb, knn_ir, bg_rgb, bg_ir, ccsum);
    se_kernel<<<NB, 256, 0, stream>>>(ccsum, Wse1, bse1, Wse2, bse2, g);
    // iter 1
    scale_w_zero<<<520, 256, 0, stream>>>(Wcomb, g, Wbf, ccsum);
    gemm_k<<<GEMM_BLKS, 256, 0, stream>>>(Abf, Wbf, Yall);
    gather_kernel<<<3600, 256, 0, stream>>>(Yall, knn_rgb, knn_ir, bg_rgb, bg_ir, ccsum);
    se_kernel<<<NB, 256, 0, stream>>>(ccsum, Wse1, bse1, Wse2, bse2, g);
    final_kernel<<<3600, 256, 0, stream>>>(cnn, g, gamma, out);
}

// Round 16
// 203.746 us; speedup vs baseline: 1.2621x; 1.0233x over previous
//
#include <hip/hip_runtime.h>
#include <hip/hip_bf16.h>

#define NB 4
#define CH 256
#define HWT 3600
#define KNN 8
#define POSB 16
#define MPAD 3712

#define SSEGP 16     // knn segments (225 candidates each)
#define CAND 225
#define RROWS 512    // rows per block: 256 threads x 2

#define GEMM_BLKS 928     // 232 * NB
#define MERGE_BLKS 458    // 450 merge + 8 zero

typedef __attribute__((ext_vector_type(8))) __bf16 bf16x8;
typedef __attribute__((ext_vector_type(4))) float f32x4;
typedef __attribute__((ext_vector_type(4))) unsigned u32x4;

__device__ inline float med3f(float a, float b, float c) {
    return __builtin_amdgcn_fmed3f(a, b, c);
}

__device__ __forceinline__ void insert8(float* best, float kf) {
    best[7] = med3f(best[6], best[7], kf);
    best[6] = med3f(best[5], best[6], kf);
    best[5] = med3f(best[4], best[5], kf);
    best[4] = med3f(best[3], best[4], kf);
    best[3] = med3f(best[2], best[3], kf);
    best[2] = med3f(best[1], best[2], kf);
    best[1] = med3f(best[0], best[1], kf);
    best[0] = fminf(best[0], kf);
}

// ================= gemm body =================

__device__ __forceinline__ void gemm_body(int lid, int n, size_t wstride,
                                          const __hip_bfloat16* __restrict__ Abf,
                                          const __hip_bfloat16* __restrict__ Wbf,
                                          __hip_bfloat16* __restrict__ Yall,
                                          char* smem) {
    char* sA = smem;
    char* sB = smem + 16384;
    int w = (lid & 7) * 29 + (lid >> 3);
    int m0 = (w >> 3) * 128;
    int o0 = (w & 7) * 128;
    int t = threadIdx.x;
    int lane = t & 63, wid = t >> 6;
    int wm = wid >> 1, wo = wid & 1;

    const __hip_bfloat16* Ab = Abf + (size_t)n * MPAD * CH;
    const __hip_bfloat16* Wb = Wbf + (size_t)n * wstride;

    f32x4 acc[4][4] = {};

    int srow = t >> 3;
    int sslot = t & 7;
    int swz = (sslot ^ (srow & 7)) << 4;
    int fr = lane & 15;
    int kg = lane >> 4;
    int p = lane & 7;

    uint4 av[4], bv[4];
    auto load_tile = [&](int ks) {
#pragma unroll
        for (int r = 0; r < 4; ++r) {
            int row = srow + 32 * r;
            av[r] = *(const uint4*)(Ab + ((size_t)(m0 + row)) * CH + ks * 64 + sslot * 8);
            bv[r] = *(const uint4*)(Wb + ((size_t)(o0 + row)) * CH + ks * 64 + sslot * 8);
        }
    };
    load_tile(0);

    for (int ks = 0; ks < 4; ++ks) {
        __syncthreads();
#pragma unroll
        for (int r = 0; r < 4; ++r) {
            int row = srow + 32 * r;
            *(uint4*)(sA + row * 128 + swz) = av[r];
            *(uint4*)(sB + row * 128 + swz) = bv[r];
        }
        __syncthreads();
        if (ks < 3) load_tile(ks + 1);
#pragma unroll
        for (int kk = 0; kk < 2; ++kk) {
            bf16x8 hf[4], wf[4];
            int slot = kk * 4 + kg;
            int inrow = (slot ^ p) << 4;
#pragma unroll
            for (int f = 0; f < 4; ++f) {
                hf[f] = *(const bf16x8*)(sA + (wm * 64 + f * 16 + fr) * 128 + inrow);
                wf[f] = *(const bf16x8*)(sB + (wo * 64 + f * 16 + fr) * 128 + inrow);
            }
#pragma unroll
            for (int fa = 0; fa < 4; ++fa)
#pragma unroll
                for (int fb = 0; fb < 4; ++fb)
                    acc[fa][fb] = __builtin_amdgcn_mfma_f32_16x16x32_bf16(
                        wf[fa], hf[fb], acc[fa][fb], 0, 0, 0);
        }
    }

    __syncthreads();
#pragma unroll
    for (int fa = 0; fa < 4; ++fa)
#pragma unroll
        for (int fb = 0; fb < 4; ++fb) {
            int ml = wm * 64 + fb * 16 + fr;
            int ob = (wo * 64 + fa * 16 + kg * 4) * 2;
            f32x4 v = acc[fa][fb];
            union { ushort4 u; __hip_bfloat16 h[4]; } pk;
            pk.h[0] = __float2bfloat16(v.x);
            pk.h[1] = __float2bfloat16(v.y);
            pk.h[2] = __float2bfloat16(v.z);
            pk.h[3] = __float2bfloat16(v.w);
            int swzb = (ob & ~15) ^ ((ml & 15) << 4);
            *(ushort4*)(smem + ml * 256 + swzb + (ob & 15)) = pk.u;
        }
    __syncthreads();
    __hip_bfloat16* Y = Yall + (size_t)n * HWT * 1024;
    int colb = (t & 15) * 16;
#pragma unroll
    for (int i = 0; i < 8; ++i) {
        int row = i * 16 + (t >> 4);
        int grow = m0 + row;
        if (grow < HWT) {
            u32x4 v = *(const u32x4*)(smem + row * 256 + (colb ^ ((row & 15) << 4)));
            __builtin_nontemporal_store(v, (u32x4*)((char*)Y + (size_t)grow * 2048 + o0 * 2 + colb));
        }
    }
}

// ================= merge body (+ ccsum zero) =================
__device__ __forceinline__ void merge_body(int mbid,
                                           const unsigned* __restrict__ partial,
                                           int* __restrict__ knn_rgb,
                                           int* __restrict__ knn_ir,
                                           float* __restrict__ ccsum) {
    if (mbid >= 450) {
        int e = (mbid - 450) * 256 + threadIdx.x;
        if (e < NB * 512) ccsum[e] = 0.f;
        return;
    }
    int tid = mbid * 256 + threadIdx.x;
    int rid = tid >> 1, sub = tid & 1;
    int nm = rid / HWT, row = rid - nm * HWT;
    const float BIG = __uint_as_float(0x7F000000u);
    float best[8];
#pragma unroll
    for (int i = 0; i < 8; ++i) best[i] = BIG;
    for (int s = sub; s < SSEGP; s += 2) {
        const unsigned* p = partial + (((size_t)(nm * SSEGP + s)) * HWT + row) * 8;
#pragma unroll
        for (int w = 0; w < 2; ++w) {
            uint4 v = ((const uint4*)p)[w];
            unsigned vv[4] = { v.x, v.y, v.z, v.w };
#pragma unroll
            for (int e = 0; e < 4; ++e) insert8(best, __uint_as_float(vv[e]));
        }
    }
    float other[8];
#pragma unroll
    for (int i = 0; i < 8; ++i) other[i] = __shfl_xor(best[i], 1);
#pragma unroll
    for (int i = 0; i < 8; ++i) insert8(best, other[i]);
    if (sub == 0) {
        int mod = nm / NB, n = nm - mod * NB;
        int* o = (mod == 0 ? knn_rgb : knn_ir) + ((size_t)n * HWT + row) * KNN;
#pragma unroll
        for (int i = 0; i < 8; ++i) o[i] = (int)(__float_as_uint(best[i]) & 0xFFFu);
    }
}

// iter-0: gemm (wstride=0, shared W) + knn merge + ccsum zero, one launch
__global__ __launch_bounds__(256) void gemm_merge(const __hip_bfloat16* __restrict__ Abf,
                                                  const __hip_bfloat16* __restrict__ Wbf,
                                                  __hip_bfloat16* __restrict__ Yall,
                                                  const unsigned* __restrict__ partial,
                                                  int* __restrict__ knn_rgb,
                                                  int* __restrict__ knn_ir,
                                                  float* __restrict__ ccsum) {
    __shared__ char smem[32768];
    int bid = blockIdx.x;
    if (bid < GEMM_BLKS) {
        gemm_body(bid % 232, bid / 232, 0, Abf, Wbf, Yall, smem);
    } else {
        merge_body(bid - GEMM_BLKS, partial, knn_rgb, knn_ir, ccsum);
    }
}

__global__ __launch_bounds__(256) void gemm_k(const __hip_bfloat16* __restrict__ Abf,
                                              const __hip_bfloat16* __restrict__ Wbf,
                                              __hip_bfloat16* __restrict__ Yall) {
    __shared__ char smem[32768];
    int gid = blockIdx.x;
    gemm_body(gid % 232, gid / 232, (size_t)1024 * CH, Abf, Wbf, Yall, smem);
}

// ================= kNN main v7 (round-15, kept) =================
__global__ __launch_bounds__(256) void knn_main(const float* __restrict__ xpack,
                                                unsigned* __restrict__ partial) {
    int seg = blockIdx.x, rb = blockIdx.y, nm = blockIdx.z;
    int t = threadIdx.x;
    const float* xp = xpack + (size_t)nm * HWT * 8;
    int j0 = seg * CAND;

    int r0 = rb * RROWS + t;
    int r1 = r0 + 256;
    bool act0 = (r0 < HWT);
    bool act1 = (r1 < HWT);
    int rr0 = act0 ? r0 : 0;
    int rr1 = act1 ? r1 : 0;
    float4 a0 = ((const float4*)xp)[(size_t)rr0 * 2];
    float4 b0 = ((const float4*)xp)[(size_t)rr0 * 2 + 1];
    float4 a1 = ((const float4*)xp)[(size_t)rr1 * 2];
    float4 b1 = ((const float4*)xp)[(size_t)rr1 * 2 + 1];
    float s00 = -2.f * a0.x, s01 = -2.f * a0.y, s02 = -2.f * a0.z, s03 = -2.f * a0.w;
    float s04 = -2.f * b0.x;
    float s10 = -2.f * a1.x, s11 = -2.f * a1.y, s12 = -2.f * a1.z, s13 = -2.f * a1.w;
    float s14 = -2.f * b1.x;
    float rq0 = b0.y + 1.0f, rq1 = b1.y + 1.0f;

    const float BIG = __uint_as_float(0x7F000000u);
    float bst0[8], bst1[8];
#pragma unroll
    for (int i = 0; i < 8; ++i) { bst0[i] = BIG; bst1[i] = BIG; }

    const float* cp = xp + (size_t)j0 * 8;
    unsigned jg0 = (unsigned)j0;
#pragma unroll 5
    for (int jj = 0; jj < CAND; ++jj) {
        float c0 = cp[0], c1 = cp[1], c2 = cp[2], c3 = cp[3], c4 = cp[4], cq = cp[5];
        cp += 8;
        unsigned jg = jg0 + jj;
        float d0 = fmaf(c0, s00, rq0);
        d0 = fmaf(c1, s01, d0);
        d0 = fmaf(c2, s02, d0);
        d0 = fmaf(c3, s03, d0);
        d0 = fmaf(c4, s04, d0);
        float e0 = d0 + cq;
        float d1 = fmaf(c0, s10, rq1);
        d1 = fmaf(c1, s11, d1);
        d1 = fmaf(c2, s12, d1);
        d1 = fmaf(c3, s13, d1);
        d1 = fmaf(c4, s14, d1);
        float e1 = d1 + cq;
        float k0 = __uint_as_float((__float_as_uint(e0) & 0xFFFFF000u) | jg);
        float k1 = __uint_as_float((__float_as_uint(e1) & 0xFFFFF000u) | jg);
        insert8(bst0, k0);
        insert8(bst1, k1);
    }
    if (act0) {
        unsigned* o = partial + (((size_t)(nm * SSEGP + seg)) * HWT + r0) * 8;
        ((uint4*)o)[0] = uint4{ __float_as_uint(bst0[0]), __float_as_uint(bst0[1]),
                                __float_as_uint(bst0[2]), __float_as_uint(bst0[3]) };
        ((uint4*)o)[1] = uint4{ __float_as_uint(bst0[4]), __float_as_uint(bst0[5]),
                                __float_as_uint(bst0[6]), __float_as_uint(bst0[7]) };
    }
    if (act1) {
        unsigned* o1 = partial + (((size_t)(nm * SSEGP + seg)) * HWT + r1) * 8;
        ((uint4*)o1)[0] = uint4{ __float_as_uint(bst1[0]), __float_as_uint(bst1[1]),
                                 __float_as_uint(bst1[2]), __float_as_uint(bst1[3]) };
        ((uint4*)o1)[1] = uint4{ __float_as_uint(bst1[4]), __float_as_uint(bst1[5]),
                                 __float_as_uint(bst1[6]), __float_as_uint(bst1[7]) };
    }
}

// ================= fusedA prolog =================
__global__ __launch_bounds__(256) void fusedA(const float* __restrict__ cnn,
                                              __hip_bfloat16* __restrict__ Abf,
                                              const float* __restrict__ Wg_rgb,
                                              const float* __restrict__ Wg_ir,
                                              float* __restrict__ Wcomb,
                                              float* __restrict__ g,
                                              __hip_bfloat16* __restrict__ Wbf,
                                              const float* __restrict__ rgb,
                                              const float* __restrict__ ir,
                                              float* __restrict__ xpack) {
    int bid = blockIdx.x;
    int t = threadIdx.x;
    if (bid < GEMM_BLKS) {
        __shared__ float st[64][65];
        int n = bid / 232;
        int rem = bid - n * 232;
        int k0 = (rem / 58) * 64;
        int m0 = (rem % 58) * 64;
        const float* src = cnn + (size_t)n * CH * HWT;
#pragma unroll
        for (int r = 0; r < 4; ++r) {
            int kl = r * 16 + (t >> 4);
            int ms = (t & 15) * 4;
            float4 v = {0.f, 0.f, 0.f, 0.f};
            if (m0 + ms < HWT) v = *(const float4*)(src + (size_t)(k0 + kl) * HWT + m0 + ms);
            st[ms + 0][kl] = v.x; st[ms + 1][kl] = v.y;
            st[ms + 2][kl] = v.z; st[ms + 3][kl] = v.w;
        }
        __syncthreads();
        int m = t >> 2, kg = (t & 3) * 16;
        union { uint4 u[2]; __hip_bfloat16 h[16]; } pk;
#pragma unroll
        for (int i = 0; i < 16; ++i) pk.h[i] = __float2bfloat16(st[m][kg + i]);
        __hip_bfloat16* dst = Abf + ((size_t)n * MPAD + m0 + m) * CH + k0 + kg;
        ((uint4*)dst)[0] = pk.u[0];
        ((uint4*)dst)[1] = pk.u[1];
    } else if (bid < GEMM_BLKS + 1024) {
        int e = (bid - GEMM_BLKS) * 256 + t;
        int o = e >> 8, j = e & 255;
        float v;
        if (o < 256)      v = Wg_rgb[o * 512 + j] + Wg_rgb[o * 512 + 256 + j];
        else if (o < 512) v = Wg_rgb[(o - 256) * 512 + 256 + j];
        else if (o < 768) v = Wg_ir[(o - 512) * 512 + j] + Wg_ir[(o - 512) * 512 + 256 + j];
        else              v = Wg_ir[(o - 768) * 512 + 256 + j];
        Wcomb[e] = v;
        Wbf[e] = __float2bfloat16(v);      // iter0: g == 1; single shared copy
        if (e < NB * CH) g[e] = 1.0f;
    } else {
        int e = (bid - GEMM_BLKS - 1024) * 256 + t;
        if (e < 2 * NB * HWT) {
            int nm = e / HWT, j = e - nm * HWT;
            int mod = nm / NB, n = nm - mod * NB;
            const float* x = (mod == 0 ? rgb : ir) + (size_t)n * 5 * HWT;
            float v[5], q = 0.f;
#pragma unroll
            for (int d = 0; d < 5; ++d) { v[d] = x[d * HWT + j]; q = fmaf(v[d], v[d], q); }
            float* o = xpack + (size_t)e * 8;
#pragma unroll
            for (int d = 0; d < 5; ++d) o[d] = v[d];
            o[5] = q; o[6] = 0.f; o[7] = 0.f;
        }
    }
}

// ================= scale_w + zero (iter 1) =================
__global__ __launch_bounds__(256) void scale_w_zero(const float* __restrict__ Wcomb,
                                                    const float* __restrict__ g,
                                                    __hip_bfloat16* __restrict__ Wbf,
                                                    float* __restrict__ ccsum) {
    int bid = blockIdx.x;
    if (bid >= 512) {
        int e = (bid - 512) * 256 + threadIdx.x;
        if (e < NB * 512) ccsum[e] = 0.f;
        return;
    }
    int n = bid >> 7;
    int gid = (bid & 127) * 256 + threadIdx.x;
    int o = gid >> 5;
    int kb = (gid & 31) * 8;
    const float* w = Wcomb + o * 256 + kb;
    const float* gp = g + n * CH + kb;
    union { uint4 u; __hip_bfloat16 h[8]; } pk;
#pragma unroll
    for (int i = 0; i < 8; ++i) pk.h[i] = __float2bfloat16(w[i] * gp[i]);
    *(uint4*)(Wbf + ((size_t)n * 1024 + o) * CH + kb) = pk.u;
}

// ================= gather: XCD-pinned channel-slice groups (round-14, kept) =================
__global__ __launch_bounds__(256) void gather_kernel(const __hip_bfloat16* __restrict__ Yall,
                                                     const int* __restrict__ knn_rgb,
                                                     const int* __restrict__ knn_ir,
                                                     const float* __restrict__ b_rgb,
                                                     const float* __restrict__ b_ir,
                                                     float* __restrict__ ccsum) {
    int lid = blockIdx.x;
    int grp = lid & 15, sub = lid >> 4;
    int n = ((grp >> 3) & 1) | (((grp >> 2) & 1) << 1);
    int mod = (grp >> 1) & 1;
    int chalf = grp & 1;
    int hwbase = sub * 16;
    int t = threadIdx.x;
    int psub = t >> 6;
    int pr = t & 63;
    int cp = chalf * 128 + pr * 2;
    __shared__ int sidx[16][2][KNN];
    __shared__ float red[4][64][2];
    {
        int p = t >> 4, rem = t & 15;
        int hw = hwbase + p;
        int v;
        if (rem < 8) v = knn_rgb[((size_t)n * HWT + hw) * KNN + rem];
        else         v = knn_ir[((size_t)n * HWT + hw) * KNN + (rem - 8)];
        sidx[p][rem >> 3][rem & 7] = v;
    }
    __syncthreads();
    const float* bias = mod ? b_ir : b_rgb;
    float b0 = bias[cp], b1 = bias[cp + 1];
    float acc0 = 0.f, acc1 = 0.f;
    const __hip_bfloat16* Y = Yall + (size_t)n * HWT * 1024;
    int offA = mod * 512 + cp;
    int offB = mod * 512 + 256 + cp;
    for (int p = psub * 4; p < psub * 4 + 4; ++p) {
        float m0 = 0.f, m1 = 0.f;
#pragma unroll
        for (int k = 0; k < KNN; ++k) {
            int jA = sidx[p][mod][k];
            int jB = sidx[p][mod ^ 1][k];
            unsigned u1 = *(const unsigned*)(Y + (size_t)jA * 1024 + offA);
            unsigned u2 = *(const unsigned*)(Y + (size_t)jB * 1024 + offB);
            float a0 = __uint_as_float(u1 << 16);
            float a1 = __uint_as_float(u1 & 0xFFFF0000u);
            float c0 = __uint_as_float(u2 << 16);
            float c1 = __uint_as_float(u2 & 0xFFFF0000u);
            m0 = fmaxf(m0, a0 - c0 + b0);
            m1 = fmaxf(m1, a1 - c1 + b1);
        }
        acc0 += m0;
        acc1 += m1;
    }
    if (psub) { red[psub][pr][0] = acc0; red[psub][pr][1] = acc1; }
    __syncthreads();
    if (psub == 0) {
#pragma unroll
        for (int q = 1; q < 4; ++q) {
            acc0 += red[q][pr][0];
            acc1 += red[q][pr][1];
        }
        atomicAdd(&ccsum[n * 512 + mod * 256 + cp], acc0);
        atomicAdd(&ccsum[n * 512 + mod * 256 + cp + 1], acc1);
    }
}

__global__ __launch_bounds__(256) void se_kernel(const float* __restrict__ ccsum,
                                                 const float* __restrict__ W1,
                                                 const float* __restrict__ b1,
                                                 const float* __restrict__ W2,
                                                 const float* __restrict__ b2,
                                                 float* __restrict__ g) {
    int n = blockIdx.x;
    int t = threadIdx.x;
    __shared__ float hid[16];
    __shared__ float cc[512];
    cc[t] = ccsum[n * 512 + t] * (1.0f / HWT);
    cc[256 + t] = ccsum[n * 512 + 256 + t] * (1.0f / HWT);
    __syncthreads();
    if (t < 16) {
        float s = b1[t];
        for (int j = 0; j < 512; ++j) s = fmaf(W1[t * 512 + j], cc[j], s);
        hid[t] = fmaxf(s, 0.f);
    }
    __syncthreads();
    float s = b2[t];
#pragma unroll
    for (int q = 0; q < 16; ++q) s = fmaf(W2[t * 16 + q], hid[q], s);
    float se = 1.0f / (1.0f + expf(-s));
    g[n * CH + t] *= se;
}

__global__ void final_kernel(const float* __restrict__ cnn, const float* __restrict__ g,
                             const float* __restrict__ gamma, float* __restrict__ out) {
    int t = blockIdx.x * blockDim.x + threadIdx.x;
    if (t >= NB * CH * HWT / 4) return;
    int nc = (t * 4) / HWT;
    float4 x = ((const float4*)cnn)[t];
    float s = gamma[0] * g[nc] + 1.0f;
    float4 o;
    o.x = fmaxf(s * x.x, 0.f);
    o.y = fmaxf(s * x.y, 0.f);
    o.z = fmaxf(s * x.z, 0.f);
    o.w = fmaxf(s * x.w, 0.f);
    ((float4*)out)[t] = o;
}

extern "C" void kernel_launch(void* const* d_in, const int* in_sizes, int n_in,
                              void* d_out, int out_size, void* d_ws, size_t ws_size,
                              hipStream_t stream) {
    const float* cnn    = (const float*)d_in[0];
    const float* rgb    = (const float*)d_in[1];
    const float* ir     = (const float*)d_in[2];
    const float* Wg_rgb = (const float*)d_in[3];
    const float* bg_rgb = (const float*)d_in[4];
    const float* Wg_ir  = (const float*)d_in[5];
    const float* bg_ir  = (const float*)d_in[6];
    const float* Wse1   = (const float*)d_in[7];
    const float* bse1   = (const float*)d_in[8];
    const float* Wse2   = (const float*)d_in[9];
    const float* bse2   = (const float*)d_in[10];
    const float* gamma  = (const float*)d_in[11];
    float* out = (float*)d_out;

    char* ws = (char*)d_ws;
    size_t off = 0;
    float* xpack = (float*)(ws + off); off += (size_t)2 * NB * HWT * 8 * 4;
    int* knn_rgb = (int*)(ws + off); off += (size_t)NB * HWT * KNN * 4;
    int* knn_ir  = (int*)(ws + off); off += (size_t)NB * HWT * KNN * 4;
    float* Wcomb = (float*)(ws + off); off += (size_t)1024 * 256 * 4;
    __hip_bfloat16* Wbf = (__hip_bfloat16*)(ws + off); off += (size_t)NB * 1024 * CH * 2;
    __hip_bfloat16* Abf = (__hip_bfloat16*)(ws + off); off += (size_t)NB * MPAD * CH * 2;
    __hip_bfloat16* Yall = (__hip_bfloat16*)(ws + off); off += (size_t)NB * HWT * 1024 * 2;
    unsigned* partial = (unsigned*)(ws + off);
    off += (size_t)2 * NB * SSEGP * HWT * 8 * 4;     // 14.7 MB
    float* ccsum = (float*)(ws + off); off += (size_t)NB * 512 * 4;
    float* g     = (float*)(ws + off); off += (size_t)NB * CH * 4;

    // prolog: convert_a + Wcomb/Wbf(shared it0)/g + knn_prep
    fusedA<<<GEMM_BLKS + 1024 + 113, 256, 0, stream>>>(cnn, Abf, Wg_rgb, Wg_ir, Wcomb, g,
                                                       Wbf, rgb, ir, xpack);
    knn_main<<<dim3(SSEGP, 8, 2 * NB), 256, 0, stream>>>(xpack, partial);
    // iter 0: gemm (wstride=0, shared W) + knn merge + ccsum zero in one launch
    gemm_merge<<<GEMM_BLKS + MERGE_BLKS, 256, 0, stream>>>(Abf, Wbf, Yall, partial,
                                                           knn_rgb, knn_ir, ccsum);
    gather_kernel<<<3600, 256, 0, stream>>>(Yall, knn_rgb, knn_ir, bg_rgb, bg_ir, ccsum);
    se_kernel<<<NB, 256, 0, stream>>>(ccsum, Wse1, bse1, Wse2, bse2, g);
    // iter 1
    scale_w_zero<<<520, 256, 0, stream>>>(Wcomb, g, Wbf, ccsum);
    gemm_k<<<GEMM_BLKS, 256, 0, stream>>>(Abf, Wbf, Yall);
    gather_kernel<<<3600, 256, 0, stream>>>(Yall, knn_rgb, knn_ir, bg_rgb, bg_ir, ccsum);
    se_kernel<<<NB, 256, 0, stream>>>(ccsum, Wse1, bse1, Wse2, bse2, g);
    final_kernel<<<3600, 256, 0, stream>>>(cnn, g, gamma, out);
}

// Round 17
// 202.846 us; speedup vs baseline: 1.2677x; 1.0044x over previous
//
#include <hip/hip_runtime.h>
#include <hip/hip_bf16.h>

#define NB 4
#define CH 256
#define HWT 3600
#define KNN 8
#define POSB 16
#define MPAD 3712

#define SSEGP 16     // knn segments (225 candidates each)
#define CAND 225
#define RROWS 512    // rows per block: 256 threads x 2

#define GEMM_BLKS 928     // 232 * NB
#define MERGE_BLKS 458    // 450 merge + 8 zero

typedef __attribute__((ext_vector_type(8))) __bf16 bf16x8;
typedef __attribute__((ext_vector_type(4))) float f32x4;
typedef __attribute__((ext_vector_type(4))) unsigned u32x4;

__device__ inline float med3f(float a, float b, float c) {
    return __builtin_amdgcn_fmed3f(a, b, c);
}

__device__ __forceinline__ void insert8(float* best, float kf) {
    best[7] = med3f(best[6], best[7], kf);
    best[6] = med3f(best[5], best[6], kf);
    best[5] = med3f(best[4], best[5], kf);
    best[4] = med3f(best[3], best[4], kf);
    best[3] = med3f(best[2], best[3], kf);
    best[2] = med3f(best[1], best[2], kf);
    best[1] = med3f(best[0], best[1], kf);
    best[0] = fminf(best[0], kf);
}

// ================= gemm body =================
// Y slab layout: Y[n][slab=o>>7][j][128ch] -> gemm block writes a contiguous
// 32KB region (each wave: 1KB contiguous); gather reads full 256B slab rows.

__device__ __forceinline__ void gemm_body(int lid, int n, size_t wstride,
                                          const __hip_bfloat16* __restrict__ Abf,
                                          const __hip_bfloat16* __restrict__ Wbf,
                                          __hip_bfloat16* __restrict__ Yall,
                                          char* smem) {
    char* sA = smem;
    char* sB = smem + 16384;
    int w = (lid & 7) * 29 + (lid >> 3);
    int m0 = (w >> 3) * 128;
    int o0 = (w & 7) * 128;
    int t = threadIdx.x;
    int lane = t & 63, wid = t >> 6;
    int wm = wid >> 1, wo = wid & 1;

    const __hip_bfloat16* Ab = Abf + (size_t)n * MPAD * CH;
    const __hip_bfloat16* Wb = Wbf + (size_t)n * wstride;

    f32x4 acc[4][4] = {};

    int srow = t >> 3;
    int sslot = t & 7;
    int swz = (sslot ^ (srow & 7)) << 4;
    int fr = lane & 15;
    int kg = lane >> 4;
    int p = lane & 7;

    uint4 av[4], bv[4];
    auto load_tile = [&](int ks) {
#pragma unroll
        for (int r = 0; r < 4; ++r) {
            int row = srow + 32 * r;
            av[r] = *(const uint4*)(Ab + ((size_t)(m0 + row)) * CH + ks * 64 + sslot * 8);
            bv[r] = *(const uint4*)(Wb + ((size_t)(o0 + row)) * CH + ks * 64 + sslot * 8);
        }
    };
    load_tile(0);

    for (int ks = 0; ks < 4; ++ks) {
        __syncthreads();
#pragma unroll
        for (int r = 0; r < 4; ++r) {
            int row = srow + 32 * r;
            *(uint4*)(sA + row * 128 + swz) = av[r];
            *(uint4*)(sB + row * 128 + swz) = bv[r];
        }
        __syncthreads();
        if (ks < 3) load_tile(ks + 1);
#pragma unroll
        for (int kk = 0; kk < 2; ++kk) {
            bf16x8 hf[4], wf[4];
            int slot = kk * 4 + kg;
            int inrow = (slot ^ p) << 4;
#pragma unroll
            for (int f = 0; f < 4; ++f) {
                hf[f] = *(const bf16x8*)(sA + (wm * 64 + f * 16 + fr) * 128 + inrow);
                wf[f] = *(const bf16x8*)(sB + (wo * 64 + f * 16 + fr) * 128 + inrow);
            }
#pragma unroll
            for (int fa = 0; fa < 4; ++fa)
#pragma unroll
                for (int fb = 0; fb < 4; ++fb)
                    acc[fa][fb] = __builtin_amdgcn_mfma_f32_16x16x32_bf16(
                        wf[fa], hf[fb], acc[fa][fb], 0, 0, 0);
        }
    }

    __syncthreads();
#pragma unroll
    for (int fa = 0; fa < 4; ++fa)
#pragma unroll
        for (int fb = 0; fb < 4; ++fb) {
            int ml = wm * 64 + fb * 16 + fr;
            int ob = (wo * 64 + fa * 16 + kg * 4) * 2;
            f32x4 v = acc[fa][fb];
            union { ushort4 u; __hip_bfloat16 h[4]; } pk;
            pk.h[0] = __float2bfloat16(v.x);
            pk.h[1] = __float2bfloat16(v.y);
            pk.h[2] = __float2bfloat16(v.z);
            pk.h[3] = __float2bfloat16(v.w);
            int swzb = (ob & ~15) ^ ((ml & 15) << 4);
            *(ushort4*)(smem + ml * 256 + swzb + (ob & 15)) = pk.u;
        }
    __syncthreads();
    char* Yslab = (char*)(Yall + (size_t)n * HWT * 1024) + (size_t)(o0 >> 7) * HWT * 256;
    int colb = (t & 15) * 16;
#pragma unroll
    for (int i = 0; i < 8; ++i) {
        int row = i * 16 + (t >> 4);
        int grow = m0 + row;
        if (grow < HWT) {
            u32x4 v = *(const u32x4*)(smem + row * 256 + (colb ^ ((row & 15) << 4)));
            *(u32x4*)(Yslab + (size_t)grow * 256 + colb) = v;
        }
    }
}

// ================= merge body (+ ccsum zero) =================
__device__ __forceinline__ void merge_body(int mbid,
                                           const unsigned* __restrict__ partial,
                                           int* __restrict__ knn_rgb,
                                           int* __restrict__ knn_ir,
                                           float* __restrict__ ccsum) {
    if (mbid >= 450) {
        int e = (mbid - 450) * 256 + threadIdx.x;
        if (e < NB * 512) ccsum[e] = 0.f;
        return;
    }
    int tid = mbid * 256 + threadIdx.x;
    int rid = tid >> 1, sub = tid & 1;
    int nm = rid / HWT, row = rid - nm * HWT;
    const float BIG = __uint_as_float(0x7F000000u);
    float best[8];
#pragma unroll
    for (int i = 0; i < 8; ++i) best[i] = BIG;
    for (int s = sub; s < SSEGP; s += 2) {
        const unsigned* p = partial + (((size_t)(nm * SSEGP + s)) * HWT + row) * 8;
#pragma unroll
        for (int w = 0; w < 2; ++w) {
            uint4 v = ((const uint4*)p)[w];
            unsigned vv[4] = { v.x, v.y, v.z, v.w };
#pragma unroll
            for (int e = 0; e < 4; ++e) insert8(best, __uint_as_float(vv[e]));
        }
    }
    float other[8];
#pragma unroll
    for (int i = 0; i < 8; ++i) other[i] = __shfl_xor(best[i], 1);
#pragma unroll
    for (int i = 0; i < 8; ++i) insert8(best, other[i]);
    if (sub == 0) {
        int mod = nm / NB, n = nm - mod * NB;
        int* o = (mod == 0 ? knn_rgb : knn_ir) + ((size_t)n * HWT + row) * KNN;
#pragma unroll
        for (int i = 0; i < 8; ++i) o[i] = (int)(__float_as_uint(best[i]) & 0xFFFu);
    }
}

// iter-0: gemm (wstride=0, shared W) + knn merge + ccsum zero, one launch
__global__ __launch_bounds__(256) void gemm_merge(const __hip_bfloat16* __restrict__ Abf,
                                                  const __hip_bfloat16* __restrict__ Wbf,
                                                  __hip_bfloat16* __restrict__ Yall,
                                                  const unsigned* __restrict__ partial,
                                                  int* __restrict__ knn_rgb,
                                                  int* __restrict__ knn_ir,
                                                  float* __restrict__ ccsum) {
    __shared__ char smem[32768];
    int bid = blockIdx.x;
    if (bid < GEMM_BLKS) {
        gemm_body(bid % 232, bid / 232, 0, Abf, Wbf, Yall, smem);
    } else {
        merge_body(bid - GEMM_BLKS, partial, knn_rgb, knn_ir, ccsum);
    }
}

__global__ __launch_bounds__(256) void gemm_k(const __hip_bfloat16* __restrict__ Abf,
                                              const __hip_bfloat16* __restrict__ Wbf,
                                              __hip_bfloat16* __restrict__ Yall) {
    __shared__ char smem[32768];
    int gid = blockIdx.x;
    gemm_body(gid % 232, gid / 232, (size_t)1024 * CH, Abf, Wbf, Yall, smem);
}

// ================= kNN main v7 (kept) =================
__global__ __launch_bounds__(256) void knn_main(const float* __restrict__ xpack,
                                                unsigned* __restrict__ partial) {
    int seg = blockIdx.x, rb = blockIdx.y, nm = blockIdx.z;
    int t = threadIdx.x;
    const float* xp = xpack + (size_t)nm * HWT * 8;
    int j0 = seg * CAND;

    int r0 = rb * RROWS + t;
    int r1 = r0 + 256;
    bool act0 = (r0 < HWT);
    bool act1 = (r1 < HWT);
    int rr0 = act0 ? r0 : 0;
    int rr1 = act1 ? r1 : 0;
    float4 a0 = ((const float4*)xp)[(size_t)rr0 * 2];
    float4 b0 = ((const float4*)xp)[(size_t)rr0 * 2 + 1];
    float4 a1 = ((const float4*)xp)[(size_t)rr1 * 2];
    float4 b1 = ((const float4*)xp)[(size_t)rr1 * 2 + 1];
    float s00 = -2.f * a0.x, s01 = -2.f * a0.y, s02 = -2.f * a0.z, s03 = -2.f * a0.w;
    float s04 = -2.f * b0.x;
    float s10 = -2.f * a1.x, s11 = -2.f * a1.y, s12 = -2.f * a1.z, s13 = -2.f * a1.w;
    float s14 = -2.f * b1.x;
    float rq0 = b0.y + 1.0f, rq1 = b1.y + 1.0f;

    const float BIG = __uint_as_float(0x7F000000u);
    float bst0[8], bst1[8];
#pragma unroll
    for (int i = 0; i < 8; ++i) { bst0[i] = BIG; bst1[i] = BIG; }

    const float* cp = xp + (size_t)j0 * 8;
    unsigned jg0 = (unsigned)j0;
#pragma unroll 5
    for (int jj = 0; jj < CAND; ++jj) {
        float c0 = cp[0], c1 = cp[1], c2 = cp[2], c3 = cp[3], c4 = cp[4], cq = cp[5];
        cp += 8;
        unsigned jg = jg0 + jj;
        float d0 = fmaf(c0, s00, rq0);
        d0 = fmaf(c1, s01, d0);
        d0 = fmaf(c2, s02, d0);
        d0 = fmaf(c3, s03, d0);
        d0 = fmaf(c4, s04, d0);
        float e0 = d0 + cq;
        float d1 = fmaf(c0, s10, rq1);
        d1 = fmaf(c1, s11, d1);
        d1 = fmaf(c2, s12, d1);
        d1 = fmaf(c3, s13, d1);
        d1 = fmaf(c4, s14, d1);
        float e1 = d1 + cq;
        float k0 = __uint_as_float((__float_as_uint(e0) & 0xFFFFF000u) | jg);
        float k1 = __uint_as_float((__float_as_uint(e1) & 0xFFFFF000u) | jg);
        insert8(bst0, k0);
        insert8(bst1, k1);
    }
    if (act0) {
        unsigned* o = partial + (((size_t)(nm * SSEGP + seg)) * HWT + r0) * 8;
        ((uint4*)o)[0] = uint4{ __float_as_uint(bst0[0]), __float_as_uint(bst0[1]),
                                __float_as_uint(bst0[2]), __float_as_uint(bst0[3]) };
        ((uint4*)o)[1] = uint4{ __float_as_uint(bst0[4]), __float_as_uint(bst0[5]),
                                __float_as_uint(bst0[6]), __float_as_uint(bst0[7]) };
    }
    if (act1) {
        unsigned* o1 = partial + (((size_t)(nm * SSEGP + seg)) * HWT + r1) * 8;
        ((uint4*)o1)[0] = uint4{ __float_as_uint(bst1[0]), __float_as_uint(bst1[1]),
                                 __float_as_uint(bst1[2]), __float_as_uint(bst1[3]) };
        ((uint4*)o1)[1] = uint4{ __float_as_uint(bst1[4]), __float_as_uint(bst1[5]),
                                 __float_as_uint(bst1[6]), __float_as_uint(bst1[7]) };
    }
}

// ================= fusedA prolog =================
__global__ __launch_bounds__(256) void fusedA(const float* __restrict__ cnn,
                                              __hip_bfloat16* __restrict__ Abf,
                                              const float* __restrict__ Wg_rgb,
                                              const float* __restrict__ Wg_ir,
                                              float* __restrict__ Wcomb,
                                              float* __restrict__ g,
                                              __hip_bfloat16* __restrict__ Wbf,
                                              const float* __restrict__ rgb,
                                              const float* __restrict__ ir,
                                              float* __restrict__ xpack) {
    int bid = blockIdx.x;
    int t = threadIdx.x;
    if (bid < GEMM_BLKS) {
        __shared__ float st[64][65];
        int n = bid / 232;
        int rem = bid - n * 232;
        int k0 = (rem / 58) * 64;
        int m0 = (rem % 58) * 64;
        const float* src = cnn + (size_t)n * CH * HWT;
#pragma unroll
        for (int r = 0; r < 4; ++r) {
            int kl = r * 16 + (t >> 4);
            int ms = (t & 15) * 4;
            float4 v = {0.f, 0.f, 0.f, 0.f};
            if (m0 + ms < HWT) v = *(const float4*)(src + (size_t)(k0 + kl) * HWT + m0 + ms);
            st[ms + 0][kl] = v.x; st[ms + 1][kl] = v.y;
            st[ms + 2][kl] = v.z; st[ms + 3][kl] = v.w;
        }
        __syncthreads();
        int m = t >> 2, kg = (t & 3) * 16;
        union { uint4 u[2]; __hip_bfloat16 h[16]; } pk;
#pragma unroll
        for (int i = 0; i < 16; ++i) pk.h[i] = __float2bfloat16(st[m][kg + i]);
        __hip_bfloat16* dst = Abf + ((size_t)n * MPAD + m0 + m) * CH + k0 + kg;
        ((uint4*)dst)[0] = pk.u[0];
        ((uint4*)dst)[1] = pk.u[1];
    } else if (bid < GEMM_BLKS + 1024) {
        int e = (bid - GEMM_BLKS) * 256 + t;
        int o = e >> 8, j = e & 255;
        float v;
        if (o < 256)      v = Wg_rgb[o * 512 + j] + Wg_rgb[o * 512 + 256 + j];
        else if (o < 512) v = Wg_rgb[(o - 256) * 512 + 256 + j];
        else if (o < 768) v = Wg_ir[(o - 512) * 512 + j] + Wg_ir[(o - 512) * 512 + 256 + j];
        else              v = Wg_ir[(o - 768) * 512 + 256 + j];
        Wcomb[e] = v;
        Wbf[e] = __float2bfloat16(v);      // iter0: g == 1; single shared copy
        if (e < NB * CH) g[e] = 1.0f;
    } else {
        int e = (bid - GEMM_BLKS - 1024) * 256 + t;
        if (e < 2 * NB * HWT) {
            int nm = e / HWT, j = e - nm * HWT;
            int mod = nm / NB, n = nm - mod * NB;
            const float* x = (mod == 0 ? rgb : ir) + (size_t)n * 5 * HWT;
            float v[5], q = 0.f;
#pragma unroll
            for (int d = 0; d < 5; ++d) { v[d] = x[d * HWT + j]; q = fmaf(v[d], v[d], q); }
            float* o = xpack + (size_t)e * 8;
#pragma unroll
            for (int d = 0; d < 5; ++d) o[d] = v[d];
            o[5] = q; o[6] = 0.f; o[7] = 0.f;
        }
    }
}

// ================= scale_w + zero (iter 1) =================
__global__ __launch_bounds__(256) void scale_w_zero(const float* __restrict__ Wcomb,
                                                    const float* __restrict__ g,
                                                    __hip_bfloat16* __restrict__ Wbf,
                                                    float* __restrict__ ccsum) {
    int bid = blockIdx.x;
    if (bid >= 512) {
        int e = (bid - 512) * 256 + threadIdx.x;
        if (e < NB * 512) ccsum[e] = 0.f;
        return;
    }
    int n = bid >> 7;
    int gid = (bid & 127) * 256 + threadIdx.x;
    int o = gid >> 5;
    int kb = (gid & 31) * 8;
    const float* w = Wcomb + o * 256 + kb;
    const float* gp = g + n * CH + kb;
    union { uint4 u; __hip_bfloat16 h[8]; } pk;
#pragma unroll
    for (int i = 0; i < 8; ++i) pk.h[i] = __float2bfloat16(w[i] * gp[i]);
    *(uint4*)(Wbf + ((size_t)n * 1024 + o) * CH + kb) = pk.u;
}

// ================= gather: XCD-pinned + slab layout =================
__global__ __launch_bounds__(256) void gather_kernel(const __hip_bfloat16* __restrict__ Yall,
                                                     const int* __restrict__ knn_rgb,
                                                     const int* __restrict__ knn_ir,
                                                     const float* __restrict__ b_rgb,
                                                     const float* __restrict__ b_ir,
                                                     float* __restrict__ ccsum) {
    int lid = blockIdx.x;
    int grp = lid & 15, sub = lid >> 4;
    int n = ((grp >> 3) & 1) | (((grp >> 2) & 1) << 1);
    int mod = (grp >> 1) & 1;
    int chalf = grp & 1;
    int hwbase = sub * 16;
    int t = threadIdx.x;
    int psub = t >> 6;
    int pr = t & 63;
    int cp = chalf * 128 + pr * 2;
    __shared__ int sidx[16][2][KNN];
    __shared__ float red[4][64][2];
    {
        int p = t >> 4, rem = t & 15;
        int hw = hwbase + p;
        int v;
        if (rem < 8) v = knn_rgb[((size_t)n * HWT + hw) * KNN + rem];
        else         v = knn_ir[((size_t)n * HWT + hw) * KNN + (rem - 8)];
        sidx[p][rem >> 3][rem & 7] = v;
    }
    __syncthreads();
    const float* bias = mod ? b_ir : b_rgb;
    float b0 = bias[cp], b1 = bias[cp + 1];
    float acc0 = 0.f, acc1 = 0.f;
    const char* Yn = (const char*)(Yall + (size_t)n * HWT * 1024);
    // slab layout: element o lives at slab o>>7, col o&127
    const char* YA = Yn + (size_t)(mod * 4 + chalf) * HWT * 256 + pr * 4;
    const char* YB = Yn + (size_t)(mod * 4 + 2 + chalf) * HWT * 256 + pr * 4;
    for (int p = psub * 4; p < psub * 4 + 4; ++p) {
        float m0 = 0.f, m1 = 0.f;
#pragma unroll
        for (int k = 0; k < KNN; ++k) {
            int jA = sidx[p][mod][k];
            int jB = sidx[p][mod ^ 1][k];
            unsigned u1 = *(const unsigned*)(YA + (size_t)jA * 256);
            unsigned u2 = *(const unsigned*)(YB + (size_t)jB * 256);
            float a0 = __uint_as_float(u1 << 16);
            float a1 = __uint_as_float(u1 & 0xFFFF0000u);
            float c0 = __uint_as_float(u2 << 16);
            float c1 = __uint_as_float(u2 & 0xFFFF0000u);
            m0 = fmaxf(m0, a0 - c0 + b0);
            m1 = fmaxf(m1, a1 - c1 + b1);
        }
        acc0 += m0;
        acc1 += m1;
    }
    if (psub) { red[psub][pr][0] = acc0; red[psub][pr][1] = acc1; }
    __syncthreads();
    if (psub == 0) {
#pragma unroll
        for (int q = 1; q < 4; ++q) {
            acc0 += red[q][pr][0];
            acc1 += red[q][pr][1];
        }
        atomicAdd(&ccsum[n * 512 + mod * 256 + cp], acc0);
        atomicAdd(&ccsum[n * 512 + mod * 256 + cp + 1], acc1);
    }
}

__global__ __launch_bounds__(256) void se_kernel(const float* __restrict__ ccsum,
                                                 const float* __restrict__ W1,
                                                 const float* __restrict__ b1,
                                                 const float* __restrict__ W2,
                                                 const float* __restrict__ b2,
                                                 float* __restrict__ g) {
    int n = blockIdx.x;
    int t = threadIdx.x;
    __shared__ float hid[16];
    __shared__ float cc[512];
    cc[t] = ccsum[n * 512 + t] * (1.0f / HWT);
    cc[256 + t] = ccsum[n * 512 + 256 + t] * (1.0f / HWT);
    __syncthreads();
    if (t < 16) {
        float s = b1[t];
        for (int j = 0; j < 512; ++j) s = fmaf(W1[t * 512 + j], cc[j], s);
        hid[t] = fmaxf(s, 0.f);
    }
    __syncthreads();
    float s = b2[t];
#pragma unroll
    for (int q = 0; q < 16; ++q) s = fmaf(W2[t * 16 + q], hid[q], s);
    float se = 1.0f / (1.0f + expf(-s));
    g[n * CH + t] *= se;
}

__global__ void final_kernel(const float* __restrict__ cnn, const float* __restrict__ g,
                             const float* __restrict__ gamma, float* __restrict__ out) {
    int t = blockIdx.x * blockDim.x + threadIdx.x;
    if (t >= NB * CH * HWT / 4) return;
    int nc = (t * 4) / HWT;
    float4 x = ((const float4*)cnn)[t];
    float s = gamma[0] * g[nc] + 1.0f;
    float4 o;
    o.x = fmaxf(s * x.x, 0.f);
    o.y = fmaxf(s * x.y, 0.f);
    o.z = fmaxf(s * x.z, 0.f);
    o.w = fmaxf(s * x.w, 0.f);
    ((float4*)out)[t] = o;
}

extern "C" void kernel_launch(void* const* d_in, const int* in_sizes, int n_in,
                              void* d_out, int out_size, void* d_ws, size_t ws_size,
                              hipStream_t stream) {
    const float* cnn    = (const float*)d_in[0];
    const float* rgb    = (const float*)d_in[1];
    const float* ir     = (const float*)d_in[2];
    const float* Wg_rgb = (const float*)d_in[3];
    const float* bg_rgb = (const float*)d_in[4];
    const float* Wg_ir  = (const float*)d_in[5];
    const float* bg_ir  = (const float*)d_in[6];
    const float* Wse1   = (const float*)d_in[7];
    const float* bse1   = (const float*)d_in[8];
    const float* Wse2   = (const float*)d_in[9];
    const float* bse2   = (const float*)d_in[10];
    const float* gamma  = (const float*)d_in[11];
    float* out = (float*)d_out;

    char* ws = (char*)d_ws;
    size_t off = 0;
    float* xpack = (float*)(ws + off); off += (size_t)2 * NB * HWT * 8 * 4;
    int* knn_rgb = (int*)(ws + off); off += (size_t)NB * HWT * KNN * 4;
    int* knn_ir  = (int*)(ws + off); off += (size_t)NB * HWT * KNN * 4;
    float* Wcomb = (float*)(ws + off); off += (size_t)1024 * 256 * 4;
    __hip_bfloat16* Wbf = (__hip_bfloat16*)(ws + off); off += (size_t)NB * 1024 * CH * 2;
    __hip_bfloat16* Abf = (__hip_bfloat16*)(ws + off); off += (size_t)NB * MPAD * CH * 2;
    __hip_bfloat16* Yall = (__hip_bfloat16*)(ws + off); off += (size_t)NB * HWT * 1024 * 2;
    unsigned* partial = (unsigned*)(ws + off);
    off += (size_t)2 * NB * SSEGP * HWT * 8 * 4;     // 14.7 MB
    float* ccsum = (float*)(ws + off); off += (size_t)NB * 512 * 4;
    float* g     = (float*)(ws + off); off += (size_t)NB * CH * 4;

    // prolog: convert_a + Wcomb/Wbf(shared it0)/g + knn_prep
    fusedA<<<GEMM_BLKS + 1024 + 113, 256, 0, stream>>>(cnn, Abf, Wg_rgb, Wg_ir, Wcomb, g,
                                                       Wbf, rgb, ir, xpack);
    knn_main<<<dim3(SSEGP, 8, 2 * NB), 256, 0, stream>>>(xpack, partial);
    // iter 0: gemm (wstride=0, shared W) + knn merge + ccsum zero in one launch
    gemm_merge<<<GEMM_BLKS + MERGE_BLKS, 256, 0, stream>>>(Abf, Wbf, Yall, partial,
                                                           knn_rgb, knn_ir, ccsum);
    gather_kernel<<<3600, 256, 0, stream>>>(Yall, knn_rgb, knn_ir, bg_rgb, bg_ir, ccsum);
    se_kernel<<<NB, 256, 0, stream>>>(ccsum, Wse1, bse1, Wse2, bse2, g);
    // iter 1
    scale_w_zero<<<520, 256, 0, stream>>>(Wcomb, g, Wbf, ccsum);
    gemm_k<<<GEMM_BLKS, 256, 0, stream>>>(Abf, Wbf, Yall);
    gather_kernel<<<3600, 256, 0, stream>>>(Yall, knn_rgb, knn_ir, bg_rgb, bg_ir, ccsum);
    se_kernel<<<NB, 256, 0, stream>>>(ccsum, Wse1, bse1, Wse2, bse2, g);
    final_kernel<<<3600, 256, 0, stream>>>(cnn, g, gamma, out);
}